// Round 1
// baseline (7695.287 us; speedup 1.0000x reference)
//
#include <hip/hip_runtime.h>
#include <math.h>

#define HH 4
#define CC 32
#define HC 128

// ---- monotone float<->uint encoding for atomicMax on floats ----
__device__ __forceinline__ unsigned fenc(float f) {
  unsigned u = __float_as_uint(f);
  return (u & 0x80000000u) ? ~u : (u | 0x80000000u);
}
__device__ __forceinline__ float fdec(unsigned e) {
  unsigned u = (e & 0x80000000u) ? (e & 0x7fffffffu) : ~e;
  return __uint_as_float(u);
}

// ---- customer_x [N,101] @ W[101,32] + b -> Y[N,32] ----
__global__ __launch_bounds__(256) void k_proj101(
    const float* __restrict__ X, const float* __restrict__ W,
    const float* __restrict__ b, float* __restrict__ Y, int N) {
  __shared__ float Ws[101 * 32];
  __shared__ float bs[32];
  for (int i = threadIdx.x; i < 101 * 32; i += 256) Ws[i] = W[i];
  if (threadIdx.x < 32) bs[threadIdx.x] = b[threadIdx.x];
  __syncthreads();
  int row = blockIdx.x * 256 + threadIdx.x;
  if (row >= N) return;
  float acc[32];
#pragma unroll
  for (int c = 0; c < 32; ++c) acc[c] = bs[c];
  const float* xr = X + (size_t)row * 101;
  for (int k = 0; k < 101; ++k) {
    float xv = xr[k];
#pragma unroll
    for (int c = 0; c < 32; ++c) acc[c] += xv * Ws[k * 32 + c];
  }
  float* yr = Y + (size_t)row * 32;
#pragma unroll
  for (int c = 0; c < 32; ++c) yr[c] = acc[c];
}

// ---- fund_x [N,1] @ W[1,32] + b -> Y[N,32] ----
__global__ __launch_bounds__(256) void k_item_proj(
    const float* __restrict__ X, const float* __restrict__ W,
    const float* __restrict__ b, float* __restrict__ Y, int N) {
  int t = blockIdx.x * 256 + threadIdx.x;
  if (t >= N * 32) return;
  int i = t >> 5, c = t & 31;
  Y[t] = X[i] * W[c] + b[c];
}

// ---- generic small GEMM: Y = act( (relu?(X + inb)) @ W[K,NO] + b ) ----
template <int K, int NO, int INRELU, int OUTRELU>
__global__ __launch_bounds__(256) void k_gemm(
    const float* __restrict__ X, const float* __restrict__ inb,
    const float* __restrict__ W, const float* __restrict__ b,
    float* __restrict__ Y, int N) {
  constexpr int JJ = NO / 32;
  constexpr int ROWS = 8;
  __shared__ float Ws[K * NO];
  __shared__ float xs[ROWS][K];
  __shared__ float bs[NO];
  __shared__ float inbs[K];
  for (int i = threadIdx.x; i < K * NO; i += 256) Ws[i] = W[i];
  for (int i = threadIdx.x; i < NO; i += 256) bs[i] = b[i];
  for (int i = threadIdx.x; i < K; i += 256) inbs[i] = inb ? inb[i] : 0.f;
  int ty = threadIdx.x >> 5;
  int tx = threadIdx.x & 31;
  for (int r0 = blockIdx.x * ROWS; r0 < N; r0 += gridDim.x * ROWS) {
    __syncthreads();
    for (int i = threadIdx.x; i < ROWS * K; i += 256) {
      int rr = i / K, kk = i % K;
      int row = r0 + rr;
      float v = (row < N) ? X[(size_t)row * K + kk] + inbs[kk] : 0.f;
      if (INRELU) v = fmaxf(v, 0.f);
      xs[rr][kk] = v;
    }
    __syncthreads();
    float acc[JJ];
#pragma unroll
    for (int j = 0; j < JJ; ++j) acc[j] = bs[tx + 32 * j];
#pragma unroll 4
    for (int k = 0; k < K; ++k) {
      float xv = xs[ty][k];
#pragma unroll
      for (int j = 0; j < JJ; ++j) acc[j] += xv * Ws[k * NO + tx + 32 * j];
    }
    int row = r0 + ty;
    if (row < N) {
      float* yr = Y + (size_t)row * NO;
#pragma unroll
      for (int j = 0; j < JJ; ++j) {
        float v = acc[j];
        if (OUTRELU) v = fmaxf(v, 0.f);
        yr[tx + 32 * j] = v;
      }
    }
  }
}

// ---- edge pass A: alpha = leakyrelu(xl[src]+xr[dst](+ef)) . att ; segment max ----
template <int USE_EF>
__global__ __launch_bounds__(256) void k_edge_alpha(
    const float* __restrict__ xl, const float* __restrict__ xr,
    const int* __restrict__ src, const int* __restrict__ dst,
    const float* __restrict__ att, const float* __restrict__ eattr,
    const float* __restrict__ We, float* __restrict__ alphaT,
    unsigned* __restrict__ amax, int E) {
  __shared__ float atts[CC];
  __shared__ float Wes[3][CC];
  int h = blockIdx.y;
  if (threadIdx.x < CC) atts[threadIdx.x] = att[h * CC + threadIdx.x];
  if (USE_EF && threadIdx.x >= 64 && threadIdx.x < 64 + 3 * CC) {
    int i = threadIdx.x - 64;
    Wes[i / CC][i % CC] = We[(i / CC) * HC + h * CC + (i % CC)];
  }
  __syncthreads();
  int e = blockIdx.x * 256 + threadIdx.x;
  if (e >= E) return;
  int s = src[e], d = dst[e];
  const float4* pl = (const float4*)(xl + (size_t)s * HC + h * CC);
  const float4* pr = (const float4*)(xr + (size_t)d * HC + h * CC);
  float a0 = 0.f, a1 = 0.f, a2 = 0.f;
  if (USE_EF) {
    const float* ea = eattr + (size_t)e * 3;
    a0 = ea[0]; a1 = ea[1]; a2 = ea[2];
  }
  float acc = 0.f;
#pragma unroll
  for (int i = 0; i < 8; ++i) {
    float4 l = pl[i];
    float4 r = pr[i];
    float xv[4] = {l.x + r.x, l.y + r.y, l.z + r.z, l.w + r.w};
#pragma unroll
    for (int q = 0; q < 4; ++q) {
      int c = i * 4 + q;
      float x = xv[q];
      if (USE_EF) x += a0 * Wes[0][c] + a1 * Wes[1][c] + a2 * Wes[2][c];
      x = (x > 0.f) ? x : 0.2f * x;
      acc += x * atts[c];
    }
  }
  alphaT[(size_t)h * E + e] = acc;
  atomicMax(amax + (size_t)d * HH + h, fenc(acc));
}

// ---- edge pass B: alpha = exp(alpha - amax[dst]); denom[dst] += alpha ----
__global__ __launch_bounds__(256) void k_edge_exps(
    const int* __restrict__ dst, float* __restrict__ alphaT,
    const unsigned* __restrict__ amax, float* __restrict__ denom, int E) {
  int h = blockIdx.y;
  int e = blockIdx.x * 256 + threadIdx.x;
  if (e >= E) return;
  int d = dst[e];
  float m = fdec(amax[(size_t)d * HH + h]);
  float v = expf(alphaT[(size_t)h * E + e] - m);
  alphaT[(size_t)h * E + e] = v;
  atomicAdd(denom + (size_t)d * HH + h, v);
}

// ---- edge pass C: agg[dst] += xl[src] * alpha/denom[dst] ----
__global__ __launch_bounds__(256) void k_edge_msg(
    const float* __restrict__ xl, const int* __restrict__ src,
    const int* __restrict__ dst, const float* __restrict__ alphaT,
    const float* __restrict__ denom, float* __restrict__ agg, int E) {
  int h = blockIdx.y;
  int e = blockIdx.x * 256 + threadIdx.x;
  if (e >= E) return;
  int s = src[e], d = dst[e];
  float w = alphaT[(size_t)h * E + e] / denom[(size_t)d * HH + h];
  const float4* pl = (const float4*)(xl + (size_t)s * HC + h * CC);
  float* pa = agg + (size_t)d * HC + h * CC;
#pragma unroll
  for (int i = 0; i < 8; ++i) {
    float4 l = pl[i];
    atomicAdd(pa + i * 4 + 0, l.x * w);
    atomicAdd(pa + i * 4 + 1, l.y * w);
    atomicAdd(pa + i * 4 + 2, l.z * w);
    atomicAdd(pa + i * 4 + 3, l.w * w);
  }
}

// ---- classifier stage 2: sigmoid(h[64] . W + b) ----
__global__ __launch_bounds__(256) void k_cls2(
    const float* __restrict__ Hm, const float* __restrict__ W,
    const float* __restrict__ b, float* __restrict__ out, int N) {
  __shared__ float Ws[64];
  if (threadIdx.x < 64) Ws[threadIdx.x] = W[threadIdx.x];
  __syncthreads();
  int row = blockIdx.x * 256 + threadIdx.x;
  if (row >= N) return;
  const float* hr = Hm + (size_t)row * 64;
  float acc = b[0];
#pragma unroll
  for (int k = 0; k < 64; ++k) acc += hr[k] * Ws[k];
  out[row] = 1.f / (1.f + expf(-acc));
}

static inline int imin(int a, int b) { return a < b ? a : b; }

extern "C" void kernel_launch(void* const* d_in, const int* in_sizes, int n_in,
                              void* d_out, int out_size, void* d_ws, size_t ws_size,
                              hipStream_t stream) {
  const float* customer_x = (const float*)d_in[0];
  const float* fund_x     = (const float*)d_in[1];
  const int*   edge_src   = (const int*)d_in[2];
  const int*   edge_dst   = (const int*)d_in[3];
  const float* edge_attr  = (const float*)d_in[4];
  const float* user_W = (const float*)d_in[5];
  const float* user_b = (const float*)d_in[6];
  const float* item_W = (const float*)d_in[7];
  const float* item_b = (const float*)d_in[8];
  const float* c1_Wl = (const float*)d_in[9];
  const float* c1_bl = (const float*)d_in[10];
  const float* c1_Wr = (const float*)d_in[11];
  const float* c1_br = (const float*)d_in[12];
  const float* c1_att = (const float*)d_in[13];
  const float* c1_We  = (const float*)d_in[14];
  const float* c1_bias = (const float*)d_in[15];
  const float* c2_Wl = (const float*)d_in[16];
  const float* c2_bl = (const float*)d_in[17];
  const float* c2_Wr = (const float*)d_in[18];
  const float* c2_br = (const float*)d_in[19];
  const float* c2_att = (const float*)d_in[20];
  const float* c2_bias = (const float*)d_in[21];
  const float* proj_W1 = (const float*)d_in[22];
  const float* proj_b1 = (const float*)d_in[23];
  const float* proj_W2 = (const float*)d_in[24];
  const float* proj_b2 = (const float*)d_in[25];
  const float* cls_W1 = (const float*)d_in[26];
  const float* cls_b1 = (const float*)d_in[27];
  const float* cls_W2 = (const float*)d_in[28];
  const float* cls_b2 = (const float*)d_in[29];

  const int Ncust = in_sizes[0] / 101;
  const int Nitem = in_sizes[1];
  const int E     = in_sizes[2];

  // workspace layout (fp32), ~167 MiB
  float* w = (float*)d_ws;
  float* user_x  = w; w += (size_t)Ncust * 32;
  float* item_x0 = w; w += (size_t)Nitem * 32;
  float* bufC    = w; w += (size_t)Ncust * HC;   // xl1 -> xr2 -> proj tmp
  float* bufD    = w; w += (size_t)Nitem * HC;   // xr1 -> xl2
  float* alphaT  = w; w += (size_t)E * HH;       // [H][E]
  unsigned* amax = (unsigned*)w; w += (size_t)Ncust * HH;
  float* denom   = w; w += (size_t)Ncust * HH;
  float* agg1    = w; w += (size_t)Nitem * HC;
  float* agg2    = w; w += (size_t)Ncust * HC;
  float* tmp_h   = w; w += (size_t)Ncust * 64;
  if ((size_t)((char*)w - (char*)d_ws) > ws_size) return;  // ws too small: bail

  float* out_scores = (float*)d_out;
  float* out_z      = out_scores + Ncust;

  const int g1 = imin((Ncust + 7) / 8, 2048);
  const int g2 = imin((Nitem + 7) / 8, 2048);
  dim3 eg((E + 255) / 256, HH);

  // node projections
  k_proj101<<<(Ncust + 255) / 256, 256, 0, stream>>>(customer_x, user_W, user_b, user_x, Ncust);
  k_item_proj<<<(Nitem * 32 + 255) / 256, 256, 0, stream>>>(fund_x, item_W, item_b, item_x0, Nitem);

  // conv1 linear parts
  k_gemm<32, 128, 0, 0><<<g1, 256, 0, stream>>>(user_x, nullptr, c1_Wl, c1_bl, bufC, Ncust);
  k_gemm<32, 128, 0, 0><<<g2, 256, 0, stream>>>(item_x0, nullptr, c1_Wr, c1_br, bufD, Nitem);

  // conv1 edge phase (customer -> fund)
  hipMemsetAsync(amax, 0, (size_t)Ncust * HH * 4, stream);
  hipMemsetAsync(denom, 0, (size_t)Ncust * HH * 4, stream);
  hipMemsetAsync(agg1, 0, (size_t)Nitem * HC * 4, stream);
  k_edge_alpha<1><<<eg, 256, 0, stream>>>(bufC, bufD, edge_src, edge_dst, c1_att,
                                          edge_attr, c1_We, alphaT, amax, E);
  k_edge_exps<<<eg, 256, 0, stream>>>(edge_dst, alphaT, amax, denom, E);
  k_edge_msg<<<eg, 256, 0, stream>>>(bufC, edge_src, edge_dst, alphaT, denom, agg1, E);

  // conv2 linear parts: xl2 = relu(agg1 + c1_bias) @ c2_Wl + c2_bl ; xr2 = user_x @ c2_Wr + c2_br
  k_gemm<128, 128, 1, 0><<<g2, 256, 0, stream>>>(agg1, c1_bias, c2_Wl, c2_bl, bufD, Nitem);
  k_gemm<32, 128, 0, 0><<<g1, 256, 0, stream>>>(user_x, nullptr, c2_Wr, c2_br, bufC, Ncust);

  // conv2 edge phase (fund -> customer, flipped edges)
  hipMemsetAsync(amax, 0, (size_t)Ncust * HH * 4, stream);
  hipMemsetAsync(denom, 0, (size_t)Ncust * HH * 4, stream);
  hipMemsetAsync(agg2, 0, (size_t)Ncust * HC * 4, stream);
  k_edge_alpha<0><<<eg, 256, 0, stream>>>(bufD, bufC, edge_dst, edge_src, c2_att,
                                          nullptr, nullptr, alphaT, amax, E);
  k_edge_exps<<<eg, 256, 0, stream>>>(edge_src, alphaT, amax, denom, E);
  k_edge_msg<<<eg, 256, 0, stream>>>(bufD, edge_dst, edge_src, alphaT, denom, agg2, E);

  // heads: user_out = agg2 + c2_bias (fused as input bias)
  k_gemm<128, 128, 0, 1><<<g1, 256, 0, stream>>>(agg2, c2_bias, proj_W1, proj_b1, bufC, Ncust);
  k_gemm<128, 128, 0, 0><<<g1, 256, 0, stream>>>(bufC, nullptr, proj_W2, proj_b2, out_z, Ncust);
  k_gemm<128, 64, 0, 1><<<g1, 256, 0, stream>>>(agg2, c2_bias, cls_W1, cls_b1, tmp_h, Ncust);
  k_cls2<<<(Ncust + 255) / 256, 256, 0, stream>>>(tmp_h, cls_W2, cls_b2, out_scores, Ncust);
}

// Round 3
// 839.860 us; speedup vs baseline: 9.1626x; 9.1626x over previous
//
#include <hip/hip_runtime.h>
#include <math.h>

#define HH 4
#define CC 32
#define HC 128

// =================== node projections ===================

__global__ __launch_bounds__(256) void k_proj101(
    const float* __restrict__ X, const float* __restrict__ W,
    const float* __restrict__ b, float* __restrict__ Y, int N) {
  __shared__ float Ws[101 * 32];
  __shared__ float bs[32];
  for (int i = threadIdx.x; i < 101 * 32; i += 256) Ws[i] = W[i];
  if (threadIdx.x < 32) bs[threadIdx.x] = b[threadIdx.x];
  __syncthreads();
  int row = blockIdx.x * 256 + threadIdx.x;
  if (row >= N) return;
  float acc[32];
#pragma unroll
  for (int c = 0; c < 32; ++c) acc[c] = bs[c];
  const float* xr = X + (size_t)row * 101;
  for (int k = 0; k < 101; ++k) {
    float xv = xr[k];
#pragma unroll
    for (int c = 0; c < 32; ++c) acc[c] += xv * Ws[k * 32 + c];
  }
  float* yr = Y + (size_t)row * 32;
#pragma unroll
  for (int c = 0; c < 32; ++c) yr[c] = acc[c];
}

__global__ __launch_bounds__(256) void k_item_proj(
    const float* __restrict__ X, const float* __restrict__ W,
    const float* __restrict__ b, float* __restrict__ Y, int N) {
  int t = blockIdx.x * 256 + threadIdx.x;
  if (t >= N * 32) return;
  int i = t >> 5, c = t & 31;
  Y[t] = X[i] * W[c] + b[c];
}

// =================== generic small GEMM ===================
// Y = act( (relu?(X + inb)) @ W[K,NO] + b )
template <int K, int NO, int INRELU, int OUTRELU>
__global__ __launch_bounds__(256) void k_gemm(
    const float* __restrict__ X, const float* __restrict__ inb,
    const float* __restrict__ W, const float* __restrict__ b,
    float* __restrict__ Y, int N) {
  constexpr int JJ = NO / 32;
  constexpr int ROWS = 8;
  __shared__ float Ws[K * NO];
  __shared__ float xs[ROWS][K];
  __shared__ float bs[NO];
  __shared__ float inbs[K];
  for (int i = threadIdx.x; i < K * NO; i += 256) Ws[i] = W[i];
  for (int i = threadIdx.x; i < NO; i += 256) bs[i] = b[i];
  for (int i = threadIdx.x; i < K; i += 256) inbs[i] = inb ? inb[i] : 0.f;
  int ty = threadIdx.x >> 5;
  int tx = threadIdx.x & 31;
  for (int r0 = blockIdx.x * ROWS; r0 < N; r0 += gridDim.x * ROWS) {
    __syncthreads();
    for (int i = threadIdx.x; i < ROWS * K; i += 256) {
      int rr = i / K, kk = i % K;
      int row = r0 + rr;
      float v = (row < N) ? X[(size_t)row * K + kk] + inbs[kk] : 0.f;
      if (INRELU) v = fmaxf(v, 0.f);
      xs[rr][kk] = v;
    }
    __syncthreads();
    float acc[JJ];
#pragma unroll
    for (int j = 0; j < JJ; ++j) acc[j] = bs[tx + 32 * j];
#pragma unroll 4
    for (int k = 0; k < K; ++k) {
      float xv = xs[ty][k];
#pragma unroll
      for (int j = 0; j < JJ; ++j) acc[j] += xv * Ws[k * NO + tx + 32 * j];
    }
    int row = r0 + ty;
    if (row < N) {
      float* yr = Y + (size_t)row * NO;
#pragma unroll
      for (int j = 0; j < JJ; ++j) {
        float v = acc[j];
        if (OUTRELU) v = fmaxf(v, 0.f);
        yr[tx + 32 * j] = v;
      }
    }
  }
}

// =================== CSR build (counting sort by key) ===================

__global__ __launch_bounds__(256) void k_hist(
    const int* __restrict__ key, int* __restrict__ hist, int E) {
  int e = blockIdx.x * 256 + threadIdx.x;
  if (e < E) atomicAdd(&hist[key[e]], 1);
}

#define SCAN_T 256
#define SCAN_V 4
#define SCAN_BLK 1024

__global__ __launch_bounds__(SCAN_T) void k_scan_local(
    const int* __restrict__ hist, int* __restrict__ starts,
    int* __restrict__ partials, int N) {
  __shared__ int sums[SCAN_T];
  int base = blockIdx.x * SCAN_BLK + threadIdx.x * SCAN_V;
  int v[SCAN_V];
  int s = 0;
#pragma unroll
  for (int i = 0; i < SCAN_V; ++i) { v[i] = (base + i < N) ? hist[base + i] : 0; s += v[i]; }
  sums[threadIdx.x] = s;
  __syncthreads();
  for (int off = 1; off < SCAN_T; off <<= 1) {
    int x = (threadIdx.x >= off) ? sums[threadIdx.x - off] : 0;
    __syncthreads();
    sums[threadIdx.x] += x;
    __syncthreads();
  }
  int run = (threadIdx.x > 0) ? sums[threadIdx.x - 1] : 0;
#pragma unroll
  for (int i = 0; i < SCAN_V; ++i) {
    if (base + i < N) starts[base + i] = run;
    run += v[i];
  }
  if (threadIdx.x == SCAN_T - 1) partials[blockIdx.x] = sums[SCAN_T - 1];
}

__global__ __launch_bounds__(SCAN_T) void k_scan_partials(int* partials, int nb) {
  __shared__ int s[SCAN_T];
  s[threadIdx.x] = (threadIdx.x < nb) ? partials[threadIdx.x] : 0;
  __syncthreads();
  for (int off = 1; off < SCAN_T; off <<= 1) {
    int x = (threadIdx.x >= off) ? s[threadIdx.x - off] : 0;
    __syncthreads();
    s[threadIdx.x] += x;
    __syncthreads();
  }
  if (threadIdx.x < nb) partials[threadIdx.x] = (threadIdx.x > 0) ? s[threadIdx.x - 1] : 0;
}

__global__ __launch_bounds__(256) void k_scan_add(
    int* __restrict__ starts, const int* __restrict__ partials,
    int* __restrict__ cursor, int N) {
  int i = blockIdx.x * 256 + threadIdx.x;
  if (i >= N) return;
  int v = starts[i] + partials[i / SCAN_BLK];
  starts[i] = v;
  cursor[i] = v;
}

__global__ __launch_bounds__(256) void k_scatter(
    const int* __restrict__ key, const int* __restrict__ other,
    int* __restrict__ cursor, int2* __restrict__ ebuf, int E) {
  int e = blockIdx.x * 256 + threadIdx.x;
  if (e >= E) return;
  int pos = atomicAdd(&cursor[key[e]], 1);
  ebuf[pos] = make_int2(other[e], e);
}

// =================== fused GATv2 edge phase ===================
// One wave per dst node: 4 heads (16-lane groups), 2 channels per lane.
// Online softmax in registers; single gather of xl[src] per edge; no atomics.
template <int USE_EF>
__global__ __launch_bounds__(256) void k_gat(
    const float* __restrict__ xl, const float* __restrict__ xr,
    const int2* __restrict__ ebuf, const int* __restrict__ starts,
    const int* __restrict__ counts, const float* __restrict__ att,
    const float* __restrict__ eattr, const float* __restrict__ We,
    float* __restrict__ agg, int N) {
  int wid = (blockIdx.x * 256 + threadIdx.x) >> 6;
  if (wid >= N) return;
  int lane = threadIdx.x & 63;
  int g = lane >> 4;          // head
  int t = lane & 15;
  int c = g * 32 + t * 2;     // channel pair owned by this lane
  float att0 = att[c], att1 = att[c + 1];
  float2 we0, we1, we2;
  if (USE_EF) {
    we0 = *(const float2*)(We + 0 * HC + c);
    we1 = *(const float2*)(We + 1 * HC + c);
    we2 = *(const float2*)(We + 2 * HC + c);
  }
  float2 xrv = *(const float2*)(xr + (size_t)wid * HC + c);
  int st = starts[wid], cnt = counts[wid];
  float m = -3.402823466e38f, dsum = 0.f, a0 = 0.f, a1 = 0.f;
  for (int i = 0; i < cnt; ++i) {
    int2 se = ebuf[st + i];               // broadcast load (same addr all lanes)
    float2 xlv = *(const float2*)(xl + (size_t)se.x * HC + c);  // coalesced 512B/wave
    float x0 = xlv.x + xrv.x, x1 = xlv.y + xrv.y;
    if (USE_EF) {
      const float* ea = eattr + (size_t)se.y * 3;
      float e0 = ea[0], e1 = ea[1], e2 = ea[2];
      x0 += e0 * we0.x + e1 * we1.x + e2 * we2.x;
      x1 += e0 * we0.y + e1 * we1.y + e2 * we2.y;
    }
    x0 = (x0 > 0.f) ? x0 : 0.2f * x0;
    x1 = (x1 > 0.f) ? x1 : 0.2f * x1;
    float p = x0 * att0 + x1 * att1;
    p += __shfl_xor(p, 1, 16);
    p += __shfl_xor(p, 2, 16);
    p += __shfl_xor(p, 4, 16);
    p += __shfl_xor(p, 8, 16);            // alpha logit, replicated in head group
    float newm = fmaxf(m, p);
    float scale = __expf(m - newm);       // first iter: exp(-inf)=0
    float w = __expf(p - newm);
    dsum = dsum * scale + w;
    a0 = a0 * scale + w * xlv.x;
    a1 = a1 * scale + w * xlv.y;
    m = newm;
  }
  float inv = (dsum > 0.f) ? 1.f / dsum : 0.f;
  *(float2*)(agg + (size_t)wid * HC + c) = make_float2(a0 * inv, a1 * inv);
}

// =================== fused classifier: sigmoid(relu((X+inb)@W1+b1)@W2+b2) ===================
__global__ __launch_bounds__(256) void k_cls_fused(
    const float* __restrict__ X, const float* __restrict__ inb,
    const float* __restrict__ W1, const float* __restrict__ b1,
    const float* __restrict__ W2, const float* __restrict__ b2,
    float* __restrict__ out, int N) {
  __shared__ float Ws[128 * 64];
  __shared__ float xs[8][128];
  __shared__ float bs[64];
  __shared__ float inbs[128];
  for (int i = threadIdx.x; i < 128 * 64; i += 256) Ws[i] = W1[i];
  for (int i = threadIdx.x; i < 64; i += 256) bs[i] = b1[i];
  for (int i = threadIdx.x; i < 128; i += 256) inbs[i] = inb[i];
  int ty = threadIdx.x >> 5, tx = threadIdx.x & 31;
  float w2a = W2[tx], w2b = W2[tx + 32];
  float bb2 = b2[0];
  for (int r0 = blockIdx.x * 8; r0 < N; r0 += gridDim.x * 8) {
    __syncthreads();
    for (int i = threadIdx.x; i < 8 * 128; i += 256) {
      int rr = i >> 7, kk = i & 127;
      int row = r0 + rr;
      xs[rr][kk] = (row < N) ? X[(size_t)row * 128 + kk] + inbs[kk] : 0.f;
    }
    __syncthreads();
    float acc0 = bs[tx], acc1 = bs[tx + 32];
#pragma unroll 4
    for (int k = 0; k < 128; ++k) {
      float xv = xs[ty][k];
      acc0 += xv * Ws[k * 64 + tx];
      acc1 += xv * Ws[k * 64 + tx + 32];
    }
    float h0 = fmaxf(acc0, 0.f), h1 = fmaxf(acc1, 0.f);
    float p = h0 * w2a + h1 * w2b;
    p += __shfl_xor(p, 1, 32);
    p += __shfl_xor(p, 2, 32);
    p += __shfl_xor(p, 4, 32);
    p += __shfl_xor(p, 8, 32);
    p += __shfl_xor(p, 16, 32);
    int row = r0 + ty;
    if (row < N && tx == 0) out[row] = 1.f / (1.f + __expf(-(p + bb2)));
  }
}

static inline int imin(int a, int b) { return a < b ? a : b; }

extern "C" void kernel_launch(void* const* d_in, const int* in_sizes, int n_in,
                              void* d_out, int out_size, void* d_ws, size_t ws_size,
                              hipStream_t stream) {
  const float* customer_x = (const float*)d_in[0];
  const float* fund_x     = (const float*)d_in[1];
  const int*   edge_src   = (const int*)d_in[2];
  const int*   edge_dst   = (const int*)d_in[3];
  const float* edge_attr  = (const float*)d_in[4];
  const float* user_W = (const float*)d_in[5];
  const float* user_b = (const float*)d_in[6];
  const float* item_W = (const float*)d_in[7];
  const float* item_b = (const float*)d_in[8];
  const float* c1_Wl = (const float*)d_in[9];
  const float* c1_bl = (const float*)d_in[10];
  const float* c1_Wr = (const float*)d_in[11];
  const float* c1_br = (const float*)d_in[12];
  const float* c1_att = (const float*)d_in[13];
  const float* c1_We  = (const float*)d_in[14];
  const float* c1_bias = (const float*)d_in[15];
  const float* c2_Wl = (const float*)d_in[16];
  const float* c2_bl = (const float*)d_in[17];
  const float* c2_Wr = (const float*)d_in[18];
  const float* c2_br = (const float*)d_in[19];
  const float* c2_att = (const float*)d_in[20];
  const float* c2_bias = (const float*)d_in[21];
  const float* proj_W1 = (const float*)d_in[22];
  const float* proj_b1 = (const float*)d_in[23];
  const float* proj_W2 = (const float*)d_in[24];
  const float* proj_b2 = (const float*)d_in[25];
  const float* cls_W1 = (const float*)d_in[26];
  const float* cls_b1 = (const float*)d_in[27];
  const float* cls_W2 = (const float*)d_in[28];
  const float* cls_b2 = (const float*)d_in[29];

  const int Ncust = in_sizes[0] / 101;
  const int Nitem = in_sizes[1];
  const int E     = in_sizes[2];

  // -------- workspace layout (~148 MiB) --------
  float* w = (float*)d_ws;
  float* user_x  = w; w += (size_t)Ncust * 32;
  float* item_x0 = w; w += (size_t)Nitem * 32;
  float* bufC    = w; w += (size_t)Ncust * HC;   // xl1 -> xr2 -> proj1 out
  float* bufD    = w; w += (size_t)Nitem * HC;   // xr1 -> xl2
  float* agg1    = w; w += (size_t)Nitem * HC;
  float* agg2    = w; w += (size_t)Ncust * HC;
  int* hist1   = (int*)w; w += Nitem;
  int* starts1 = (int*)w; w += Nitem;
  int* cursor1 = (int*)w; w += Nitem;
  int* hist2   = (int*)w; w += Ncust;
  int* starts2 = (int*)w; w += Ncust;
  int* cursor2 = (int*)w; w += Ncust;
  int* partials = (int*)w; w += 512;
  int2* ebuf1 = (int2*)w; w += (size_t)E * 2;
  int2* ebuf2 = (int2*)w; w += (size_t)E * 2;
  if ((size_t)((char*)w - (char*)d_ws) > ws_size) return;

  float* out_scores = (float*)d_out;
  float* out_z      = out_scores + Ncust;

  const int g1 = imin((Ncust + 7) / 8, 2048);
  const int g2 = imin((Nitem + 7) / 8, 2048);
  const int egrid = (E + 255) / 256;
  const int nb1 = (Nitem + SCAN_BLK - 1) / SCAN_BLK;
  const int nb2 = (Ncust + SCAN_BLK - 1) / SCAN_BLK;

  // -------- CSR build: conv1 keyed by edge_dst (funds), conv2 keyed by edge_src (customers) --------
  hipMemsetAsync(hist1, 0, (size_t)Nitem * 4, stream);
  hipMemsetAsync(hist2, 0, (size_t)Ncust * 4, stream);
  k_hist<<<egrid, 256, 0, stream>>>(edge_dst, hist1, E);
  k_hist<<<egrid, 256, 0, stream>>>(edge_src, hist2, E);
  k_scan_local<<<nb1, SCAN_T, 0, stream>>>(hist1, starts1, partials, Nitem);
  k_scan_partials<<<1, SCAN_T, 0, stream>>>(partials, nb1);
  k_scan_add<<<(Nitem + 255) / 256, 256, 0, stream>>>(starts1, partials, cursor1, Nitem);
  k_scatter<<<egrid, 256, 0, stream>>>(edge_dst, edge_src, cursor1, ebuf1, E);
  k_scan_local<<<nb2, SCAN_T, 0, stream>>>(hist2, starts2, partials, Ncust);
  k_scan_partials<<<1, SCAN_T, 0, stream>>>(partials, nb2);
  k_scan_add<<<(Ncust + 255) / 256, 256, 0, stream>>>(starts2, partials, cursor2, Ncust);
  k_scatter<<<egrid, 256, 0, stream>>>(edge_src, edge_dst, cursor2, ebuf2, E);

  // -------- node projections --------
  k_proj101<<<(Ncust + 255) / 256, 256, 0, stream>>>(customer_x, user_W, user_b, user_x, Ncust);
  k_item_proj<<<(Nitem * 32 + 255) / 256, 256, 0, stream>>>(fund_x, item_W, item_b, item_x0, Nitem);

  // -------- conv1 (customer -> fund, with edge features) --------
  k_gemm<32, 128, 0, 0><<<g1, 256, 0, stream>>>(user_x, nullptr, c1_Wl, c1_bl, bufC, Ncust);
  k_gemm<32, 128, 0, 0><<<g2, 256, 0, stream>>>(item_x0, nullptr, c1_Wr, c1_br, bufD, Nitem);
  k_gat<1><<<(Nitem + 3) / 4, 256, 0, stream>>>(bufC, bufD, ebuf1, starts1, hist1,
                                                c1_att, edge_attr, c1_We, agg1, Nitem);

  // -------- conv2 (fund -> customer, flipped edges) --------
  k_gemm<128, 128, 1, 0><<<g2, 256, 0, stream>>>(agg1, c1_bias, c2_Wl, c2_bl, bufD, Nitem);
  k_gemm<32, 128, 0, 0><<<g1, 256, 0, stream>>>(user_x, nullptr, c2_Wr, c2_br, bufC, Ncust);
  k_gat<0><<<(Ncust + 3) / 4, 256, 0, stream>>>(bufD, bufC, ebuf2, starts2, hist2,
                                                c2_att, nullptr, nullptr, agg2, Ncust);

  // -------- heads (user_out = agg2 + c2_bias fused as input bias) --------
  k_gemm<128, 128, 0, 1><<<g1, 256, 0, stream>>>(agg2, c2_bias, proj_W1, proj_b1, bufC, Ncust);
  k_gemm<128, 128, 0, 0><<<g1, 256, 0, stream>>>(bufC, nullptr, proj_W2, proj_b2, out_z, Ncust);
  k_cls_fused<<<g1, 256, 0, stream>>>(agg2, c2_bias, cls_W1, cls_b1, cls_W2, cls_b2,
                                      out_scores, Ncust);
}

// Round 4
// 800.864 us; speedup vs baseline: 9.6087x; 1.0487x over previous
//
#include <hip/hip_runtime.h>
#include <math.h>

#define HH 4
#define CC 32
#define HC 128

// =================== node projections ===================

__global__ __launch_bounds__(256) void k_proj101(
    const float* __restrict__ X, const float* __restrict__ W,
    const float* __restrict__ b, float* __restrict__ Y, int N) {
  __shared__ float Ws[101 * 32];
  __shared__ float bs[32];
  for (int i = threadIdx.x; i < 101 * 32; i += 256) Ws[i] = W[i];
  if (threadIdx.x < 32) bs[threadIdx.x] = b[threadIdx.x];
  __syncthreads();
  int row = blockIdx.x * 256 + threadIdx.x;
  if (row >= N) return;
  float acc[32];
#pragma unroll
  for (int c = 0; c < 32; ++c) acc[c] = bs[c];
  const float* xr = X + (size_t)row * 101;
  for (int k = 0; k < 101; ++k) {
    float xv = xr[k];
#pragma unroll
    for (int c = 0; c < 32; ++c) acc[c] += xv * Ws[k * 32 + c];
  }
  float* yr = Y + (size_t)row * 32;
#pragma unroll
  for (int c = 0; c < 32; ++c) yr[c] = acc[c];
}

__global__ __launch_bounds__(256) void k_item_proj(
    const float* __restrict__ X, const float* __restrict__ W,
    const float* __restrict__ b, float* __restrict__ Y, int N) {
  int t = blockIdx.x * 256 + threadIdx.x;
  if (t >= N * 32) return;
  int i = t >> 5, c = t & 31;
  Y[t] = X[i] * W[c] + b[c];
}

// =================== high-intensity tiled GEMM ===================
// Y[N,NO] = act( (relu?(X[N,K] + inb)) @ W[K,NO] + b )
// Block: 128 rows x NO cols, 256 threads, 8x8 micro-tile (NO=128).
// xsT staged k-major so fragment reads are broadcast float4s.
template <int K, int NO, int INRELU, int OUTRELU>
__global__ __launch_bounds__(256) void k_tile(
    const float* __restrict__ X, const float* __restrict__ inb,
    const float* __restrict__ W, const float* __restrict__ b,
    float* __restrict__ Y, int N) {
  __shared__ float xsT[K][132];     // [k][row], pad 4 keeps 16B alignment
  __shared__ float ws[K * NO];
  __shared__ float bs[NO];
  __shared__ float inbs[K];
  for (int i = threadIdx.x; i < K * NO; i += 256) ws[i] = W[i];
  for (int i = threadIdx.x; i < NO; i += 256) bs[i] = b[i];
  for (int i = threadIdx.x; i < K; i += 256) inbs[i] = inb ? inb[i] : 0.f;
  __syncthreads();
  int row0 = blockIdx.x * 128;
  // stage X tile transposed: lane k-contiguous global reads, 2-8 way LDS write alias
  for (int idx = threadIdx.x; idx < 128 * K; idx += 256) {
    int k = idx % K, r = idx / K;
    int row = row0 + r;
    float v = 0.f;
    if (row < N) {
      v = X[(size_t)row * K + k] + inbs[k];
      if (INRELU) v = fmaxf(v, 0.f);
    }
    xsT[k][r] = v;
  }
  __syncthreads();
  int tx = threadIdx.x & 15, ty = threadIdx.x >> 4;
  float acc[8][8];
#pragma unroll
  for (int j = 0; j < 8; ++j) {
    float bj = bs[tx * 8 + j];
#pragma unroll
    for (int i = 0; i < 8; ++i) acc[i][j] = bj;
  }
#pragma unroll 2
  for (int k = 0; k < K; ++k) {
    float4 a0 = *(const float4*)&xsT[k][ty * 8];
    float4 a1 = *(const float4*)&xsT[k][ty * 8 + 4];
    float4 b0 = *(const float4*)&ws[k * NO + tx * 8];
    float4 b1 = *(const float4*)&ws[k * NO + tx * 8 + 4];
    float av[8] = {a0.x, a0.y, a0.z, a0.w, a1.x, a1.y, a1.z, a1.w};
    float bv[8] = {b0.x, b0.y, b0.z, b0.w, b1.x, b1.y, b1.z, b1.w};
#pragma unroll
    for (int i = 0; i < 8; ++i)
#pragma unroll
      for (int j = 0; j < 8; ++j) acc[i][j] += av[i] * bv[j];
  }
#pragma unroll
  for (int i = 0; i < 8; ++i) {
    int row = row0 + ty * 8 + i;
    if (row < N) {
      float o[8];
#pragma unroll
      for (int j = 0; j < 8; ++j) o[j] = OUTRELU ? fmaxf(acc[i][j], 0.f) : acc[i][j];
      float* yr = Y + (size_t)row * NO + tx * 8;
      *(float4*)yr = make_float4(o[0], o[1], o[2], o[3]);
      *(float4*)(yr + 4) = make_float4(o[4], o[5], o[6], o[7]);
    }
  }
}

// =================== fused head: proj1 + classifier ===================
// X = agg2 (+c2_bias). Phase1: Z = relu(X@W1+b1) [128 cols].
// Phase2 (reuses staged X): h = relu(X@Wc1+bc1) [64 cols]; S = sigmoid(h@Wc2+bc2).
__global__ __launch_bounds__(256) void k_head_fused(
    const float* __restrict__ X, const float* __restrict__ inb,
    const float* __restrict__ W1, const float* __restrict__ b1,
    const float* __restrict__ Wc1, const float* __restrict__ bc1,
    const float* __restrict__ Wc2, const float* __restrict__ bc2,
    float* __restrict__ Z, float* __restrict__ S, int N) {
  __shared__ float xsT[128][132];
  __shared__ float ws[128 * 128];
  __shared__ float bs[128];
  __shared__ float bs2[64];
  __shared__ float wc2s[64];
  __shared__ float inbs[128];
  for (int i = threadIdx.x; i < 128 * 128; i += 256) ws[i] = W1[i];
  for (int i = threadIdx.x; i < 128; i += 256) { bs[i] = b1[i]; inbs[i] = inb[i]; }
  if (threadIdx.x < 64) { bs2[threadIdx.x] = bc1[threadIdx.x]; wc2s[threadIdx.x] = Wc2[threadIdx.x]; }
  __syncthreads();
  int row0 = blockIdx.x * 128;
  for (int idx = threadIdx.x; idx < 128 * 128; idx += 256) {
    int k = idx & 127, r = idx >> 7;
    int row = row0 + r;
    xsT[k][r] = (row < N) ? X[(size_t)row * 128 + k] + inbs[k] : 0.f;
  }
  __syncthreads();
  int tx = threadIdx.x & 15, ty = threadIdx.x >> 4;
  // ---- phase 1: proj1 ----
  {
    float acc[8][8];
#pragma unroll
    for (int j = 0; j < 8; ++j) {
      float bj = bs[tx * 8 + j];
#pragma unroll
      for (int i = 0; i < 8; ++i) acc[i][j] = bj;
    }
#pragma unroll 2
    for (int k = 0; k < 128; ++k) {
      float4 a0 = *(const float4*)&xsT[k][ty * 8];
      float4 a1 = *(const float4*)&xsT[k][ty * 8 + 4];
      float4 b0 = *(const float4*)&ws[k * 128 + tx * 8];
      float4 b1 = *(const float4*)&ws[k * 128 + tx * 8 + 4];
      float av[8] = {a0.x, a0.y, a0.z, a0.w, a1.x, a1.y, a1.z, a1.w};
      float bv[8] = {b0.x, b0.y, b0.z, b0.w, b1.x, b1.y, b1.z, b1.w};
#pragma unroll
      for (int i = 0; i < 8; ++i)
#pragma unroll
        for (int j = 0; j < 8; ++j) acc[i][j] += av[i] * bv[j];
    }
#pragma unroll
    for (int i = 0; i < 8; ++i) {
      int row = row0 + ty * 8 + i;
      if (row < N) {
        float* zr = Z + (size_t)row * 128 + tx * 8;
        *(float4*)zr = make_float4(fmaxf(acc[i][0], 0.f), fmaxf(acc[i][1], 0.f),
                                   fmaxf(acc[i][2], 0.f), fmaxf(acc[i][3], 0.f));
        *(float4*)(zr + 4) = make_float4(fmaxf(acc[i][4], 0.f), fmaxf(acc[i][5], 0.f),
                                         fmaxf(acc[i][6], 0.f), fmaxf(acc[i][7], 0.f));
      }
    }
  }
  // ---- phase 2: classifier (reload ws with Wc1[128,64]) ----
  __syncthreads();
  for (int i = threadIdx.x; i < 128 * 64; i += 256) ws[i] = Wc1[i];
  __syncthreads();
  float bb2 = bc2[0];
  {
    float acc2[8][4];
#pragma unroll
    for (int j = 0; j < 4; ++j) {
      float bj = bs2[tx * 4 + j];
#pragma unroll
      for (int i = 0; i < 8; ++i) acc2[i][j] = bj;
    }
#pragma unroll 2
    for (int k = 0; k < 128; ++k) {
      float4 a0 = *(const float4*)&xsT[k][ty * 8];
      float4 a1 = *(const float4*)&xsT[k][ty * 8 + 4];
      float4 w4 = *(const float4*)&ws[k * 64 + tx * 4];
      float av[8] = {a0.x, a0.y, a0.z, a0.w, a1.x, a1.y, a1.z, a1.w};
      float wv[4] = {w4.x, w4.y, w4.z, w4.w};
#pragma unroll
      for (int i = 0; i < 8; ++i)
#pragma unroll
        for (int j = 0; j < 4; ++j) acc2[i][j] += av[i] * wv[j];
    }
    float w2a = wc2s[tx * 4], w2b = wc2s[tx * 4 + 1], w2c = wc2s[tx * 4 + 2], w2d = wc2s[tx * 4 + 3];
#pragma unroll
    for (int i = 0; i < 8; ++i) {
      float p = fmaxf(acc2[i][0], 0.f) * w2a + fmaxf(acc2[i][1], 0.f) * w2b +
                fmaxf(acc2[i][2], 0.f) * w2c + fmaxf(acc2[i][3], 0.f) * w2d;
      p += __shfl_xor(p, 1, 16);
      p += __shfl_xor(p, 2, 16);
      p += __shfl_xor(p, 4, 16);
      p += __shfl_xor(p, 8, 16);
      int row = row0 + ty * 8 + i;
      if (row < N && tx == 0) S[row] = 1.f / (1.f + __expf(-(p + bb2)));
    }
  }
}

// =================== CSR build (counting sort by key) ===================

__global__ __launch_bounds__(256) void k_hist(
    const int* __restrict__ key, int* __restrict__ hist, int E) {
  int e = blockIdx.x * 256 + threadIdx.x;
  if (e < E) atomicAdd(&hist[key[e]], 1);
}

#define SCAN_T 256
#define SCAN_V 4
#define SCAN_BLK 1024

__global__ __launch_bounds__(SCAN_T) void k_scan_local(
    const int* __restrict__ hist, int* __restrict__ starts,
    int* __restrict__ partials, int N) {
  __shared__ int sums[SCAN_T];
  int base = blockIdx.x * SCAN_BLK + threadIdx.x * SCAN_V;
  int v[SCAN_V];
  int s = 0;
#pragma unroll
  for (int i = 0; i < SCAN_V; ++i) { v[i] = (base + i < N) ? hist[base + i] : 0; s += v[i]; }
  sums[threadIdx.x] = s;
  __syncthreads();
  for (int off = 1; off < SCAN_T; off <<= 1) {
    int x = (threadIdx.x >= off) ? sums[threadIdx.x - off] : 0;
    __syncthreads();
    sums[threadIdx.x] += x;
    __syncthreads();
  }
  int run = (threadIdx.x > 0) ? sums[threadIdx.x - 1] : 0;
#pragma unroll
  for (int i = 0; i < SCAN_V; ++i) {
    if (base + i < N) starts[base + i] = run;
    run += v[i];
  }
  if (threadIdx.x == SCAN_T - 1) partials[blockIdx.x] = sums[SCAN_T - 1];
}

__global__ __launch_bounds__(SCAN_T) void k_scan_partials(int* partials, int nb) {
  __shared__ int s[SCAN_T];
  s[threadIdx.x] = (threadIdx.x < nb) ? partials[threadIdx.x] : 0;
  __syncthreads();
  for (int off = 1; off < SCAN_T; off <<= 1) {
    int x = (threadIdx.x >= off) ? s[threadIdx.x - off] : 0;
    __syncthreads();
    s[threadIdx.x] += x;
    __syncthreads();
  }
  if (threadIdx.x < nb) partials[threadIdx.x] = (threadIdx.x > 0) ? s[threadIdx.x - 1] : 0;
}

__global__ __launch_bounds__(256) void k_scan_add(
    int* __restrict__ starts, const int* __restrict__ partials,
    int* __restrict__ cursor, int N) {
  int i = blockIdx.x * 256 + threadIdx.x;
  if (i >= N) return;
  int v = starts[i] + partials[i / SCAN_BLK];
  starts[i] = v;
  cursor[i] = v;
}

__global__ __launch_bounds__(256) void k_scatter(
    const int* __restrict__ key, const int* __restrict__ other,
    int* __restrict__ cursor, int2* __restrict__ ebuf, int E) {
  int e = blockIdx.x * 256 + threadIdx.x;
  if (e >= E) return;
  int pos = atomicAdd(&cursor[key[e]], 1);
  ebuf[pos] = make_int2(other[e], e);
}

// =================== fused GATv2 edge phase ===================
template <int USE_EF>
__global__ __launch_bounds__(256) void k_gat(
    const float* __restrict__ xl, const float* __restrict__ xr,
    const int2* __restrict__ ebuf, const int* __restrict__ starts,
    const int* __restrict__ counts, const float* __restrict__ att,
    const float* __restrict__ eattr, const float* __restrict__ We,
    float* __restrict__ agg, int N) {
  int wid = (blockIdx.x * 256 + threadIdx.x) >> 6;
  if (wid >= N) return;
  int lane = threadIdx.x & 63;
  int g = lane >> 4;
  int t = lane & 15;
  int c = g * 32 + t * 2;
  float att0 = att[c], att1 = att[c + 1];
  float2 we0, we1, we2;
  if (USE_EF) {
    we0 = *(const float2*)(We + 0 * HC + c);
    we1 = *(const float2*)(We + 1 * HC + c);
    we2 = *(const float2*)(We + 2 * HC + c);
  }
  float2 xrv = *(const float2*)(xr + (size_t)wid * HC + c);
  int st = starts[wid], cnt = counts[wid];
  float m = -3.402823466e38f, dsum = 0.f, a0 = 0.f, a1 = 0.f;
  for (int i = 0; i < cnt; ++i) {
    int2 se = ebuf[st + i];
    float2 xlv = *(const float2*)(xl + (size_t)se.x * HC + c);
    float x0 = xlv.x + xrv.x, x1 = xlv.y + xrv.y;
    if (USE_EF) {
      const float* ea = eattr + (size_t)se.y * 3;
      float e0 = ea[0], e1 = ea[1], e2 = ea[2];
      x0 += e0 * we0.x + e1 * we1.x + e2 * we2.x;
      x1 += e0 * we0.y + e1 * we1.y + e2 * we2.y;
    }
    x0 = (x0 > 0.f) ? x0 : 0.2f * x0;
    x1 = (x1 > 0.f) ? x1 : 0.2f * x1;
    float p = x0 * att0 + x1 * att1;
    p += __shfl_xor(p, 1, 16);
    p += __shfl_xor(p, 2, 16);
    p += __shfl_xor(p, 4, 16);
    p += __shfl_xor(p, 8, 16);
    float newm = fmaxf(m, p);
    float scale = __expf(m - newm);
    float w = __expf(p - newm);
    dsum = dsum * scale + w;
    a0 = a0 * scale + w * xlv.x;
    a1 = a1 * scale + w * xlv.y;
    m = newm;
  }
  float inv = (dsum > 0.f) ? 1.f / dsum : 0.f;
  *(float2*)(agg + (size_t)wid * HC + c) = make_float2(a0 * inv, a1 * inv);
}

static inline int imin(int a, int b) { return a < b ? a : b; }

extern "C" void kernel_launch(void* const* d_in, const int* in_sizes, int n_in,
                              void* d_out, int out_size, void* d_ws, size_t ws_size,
                              hipStream_t stream) {
  const float* customer_x = (const float*)d_in[0];
  const float* fund_x     = (const float*)d_in[1];
  const int*   edge_src   = (const int*)d_in[2];
  const int*   edge_dst   = (const int*)d_in[3];
  const float* edge_attr  = (const float*)d_in[4];
  const float* user_W = (const float*)d_in[5];
  const float* user_b = (const float*)d_in[6];
  const float* item_W = (const float*)d_in[7];
  const float* item_b = (const float*)d_in[8];
  const float* c1_Wl = (const float*)d_in[9];
  const float* c1_bl = (const float*)d_in[10];
  const float* c1_Wr = (const float*)d_in[11];
  const float* c1_br = (const float*)d_in[12];
  const float* c1_att = (const float*)d_in[13];
  const float* c1_We  = (const float*)d_in[14];
  const float* c1_bias = (const float*)d_in[15];
  const float* c2_Wl = (const float*)d_in[16];
  const float* c2_bl = (const float*)d_in[17];
  const float* c2_Wr = (const float*)d_in[18];
  const float* c2_br = (const float*)d_in[19];
  const float* c2_att = (const float*)d_in[20];
  const float* c2_bias = (const float*)d_in[21];
  const float* proj_W1 = (const float*)d_in[22];
  const float* proj_b1 = (const float*)d_in[23];
  const float* proj_W2 = (const float*)d_in[24];
  const float* proj_b2 = (const float*)d_in[25];
  const float* cls_W1 = (const float*)d_in[26];
  const float* cls_b1 = (const float*)d_in[27];
  const float* cls_W2 = (const float*)d_in[28];
  const float* cls_b2 = (const float*)d_in[29];

  const int Ncust = in_sizes[0] / 101;
  const int Nitem = in_sizes[1];
  const int E     = in_sizes[2];

  // -------- workspace layout (~148 MiB) --------
  float* w = (float*)d_ws;
  float* user_x  = w; w += (size_t)Ncust * 32;
  float* item_x0 = w; w += (size_t)Nitem * 32;
  float* bufC    = w; w += (size_t)Ncust * HC;   // xl1 -> xr2 -> proj1 out
  float* bufD    = w; w += (size_t)Nitem * HC;   // xr1 -> xl2
  float* agg1    = w; w += (size_t)Nitem * HC;
  float* agg2    = w; w += (size_t)Ncust * HC;
  int* hist1   = (int*)w; w += Nitem;
  int* starts1 = (int*)w; w += Nitem;
  int* cursor1 = (int*)w; w += Nitem;
  int* hist2   = (int*)w; w += Ncust;
  int* starts2 = (int*)w; w += Ncust;
  int* cursor2 = (int*)w; w += Ncust;
  int* partials = (int*)w; w += 512;
  int2* ebuf1 = (int2*)w; w += (size_t)E * 2;
  int2* ebuf2 = (int2*)w; w += (size_t)E * 2;
  if ((size_t)((char*)w - (char*)d_ws) > ws_size) return;

  float* out_scores = (float*)d_out;
  float* out_z      = out_scores + Ncust;

  const int egrid = (E + 255) / 256;
  const int nb1 = (Nitem + SCAN_BLK - 1) / SCAN_BLK;
  const int nb2 = (Ncust + SCAN_BLK - 1) / SCAN_BLK;
  const int nt1 = (Ncust + 127) / 128;
  const int nt2 = (Nitem + 127) / 128;

  // -------- CSR build --------
  hipMemsetAsync(hist1, 0, (size_t)Nitem * 4, stream);
  hipMemsetAsync(hist2, 0, (size_t)Ncust * 4, stream);
  k_hist<<<egrid, 256, 0, stream>>>(edge_dst, hist1, E);
  k_hist<<<egrid, 256, 0, stream>>>(edge_src, hist2, E);
  k_scan_local<<<nb1, SCAN_T, 0, stream>>>(hist1, starts1, partials, Nitem);
  k_scan_partials<<<1, SCAN_T, 0, stream>>>(partials, nb1);
  k_scan_add<<<(Nitem + 255) / 256, 256, 0, stream>>>(starts1, partials, cursor1, Nitem);
  k_scatter<<<egrid, 256, 0, stream>>>(edge_dst, edge_src, cursor1, ebuf1, E);
  k_scan_local<<<nb2, SCAN_T, 0, stream>>>(hist2, starts2, partials, Ncust);
  k_scan_partials<<<1, SCAN_T, 0, stream>>>(partials, nb2);
  k_scan_add<<<(Ncust + 255) / 256, 256, 0, stream>>>(starts2, partials, cursor2, Ncust);
  k_scatter<<<egrid, 256, 0, stream>>>(edge_src, edge_dst, cursor2, ebuf2, E);

  // -------- node projections --------
  k_proj101<<<(Ncust + 255) / 256, 256, 0, stream>>>(customer_x, user_W, user_b, user_x, Ncust);
  k_item_proj<<<(Nitem * 32 + 255) / 256, 256, 0, stream>>>(fund_x, item_W, item_b, item_x0, Nitem);

  // -------- conv1 (customer -> fund, edge features) --------
  k_tile<32, 128, 0, 0><<<nt1, 256, 0, stream>>>(user_x, nullptr, c1_Wl, c1_bl, bufC, Ncust);
  k_tile<32, 128, 0, 0><<<nt2, 256, 0, stream>>>(item_x0, nullptr, c1_Wr, c1_br, bufD, Nitem);
  k_gat<1><<<(Nitem + 3) / 4, 256, 0, stream>>>(bufC, bufD, ebuf1, starts1, hist1,
                                                c1_att, edge_attr, c1_We, agg1, Nitem);

  // -------- conv2 (fund -> customer, flipped edges) --------
  k_tile<128, 128, 1, 0><<<nt2, 256, 0, stream>>>(agg1, c1_bias, c2_Wl, c2_bl, bufD, Nitem);
  k_tile<32, 128, 0, 0><<<nt1, 256, 0, stream>>>(user_x, nullptr, c2_Wr, c2_br, bufC, Ncust);
  k_gat<0><<<(Ncust + 3) / 4, 256, 0, stream>>>(bufD, bufC, ebuf2, starts2, hist2,
                                                c2_att, nullptr, nullptr, agg2, Ncust);

  // -------- heads --------
  k_head_fused<<<nt1, 256, 0, stream>>>(agg2, c2_bias, proj_W1, proj_b1,
                                        cls_W1, cls_b1, cls_W2, cls_b2,
                                        bufC, out_scores, Ncust);
  k_tile<128, 128, 0, 0><<<nt1, 256, 0, stream>>>(bufC, nullptr, proj_W2, proj_b2, out_z, Ncust);
}

// Round 5
// 639.615 us; speedup vs baseline: 12.0311x; 1.2521x over previous
//
#include <hip/hip_runtime.h>
#include <math.h>

#define HH 4
#define CC 32
#define HC 128

// =================== node projections ===================

__global__ __launch_bounds__(256) void k_proj101(
    const float* __restrict__ X, const float* __restrict__ W,
    const float* __restrict__ b, float* __restrict__ Y, int N) {
  __shared__ float Ws[101 * 32];
  __shared__ float bs[32];
  for (int i = threadIdx.x; i < 101 * 32; i += 256) Ws[i] = W[i];
  if (threadIdx.x < 32) bs[threadIdx.x] = b[threadIdx.x];
  __syncthreads();
  int row = blockIdx.x * 256 + threadIdx.x;
  if (row >= N) return;
  float acc[32];
#pragma unroll
  for (int c = 0; c < 32; ++c) acc[c] = bs[c];
  const float* xr = X + (size_t)row * 101;
  for (int k = 0; k < 101; ++k) {
    float xv = xr[k];
#pragma unroll
    for (int c = 0; c < 32; ++c) acc[c] += xv * Ws[k * 32 + c];
  }
  float* yr = Y + (size_t)row * 32;
#pragma unroll
  for (int c = 0; c < 32; ++c) yr[c] = acc[c];
}

__global__ __launch_bounds__(256) void k_item_proj(
    const float* __restrict__ X, const float* __restrict__ W,
    const float* __restrict__ b, float* __restrict__ Y, int N) {
  int t = blockIdx.x * 256 + threadIdx.x;
  if (t >= N * 32) return;
  int i = t >> 5, c = t & 31;
  Y[t] = X[i] * W[c] + b[c];
}

// =================== K-chunked tiled GEMM (8x8 micro-tile) ===================
// Y[N,128] = act( (relu?(X[N,K] + inb)) @ W[K,128] + b )
// 256 threads, 128-row x 128-col block tile. K staged in 32-wide chunks so
// LDS stays ~34KB -> 4 blocks/CU (vs 134KB -> 1 block/CU in R4).
template <int K, int INRELU, int OUTRELU>
__global__ __launch_bounds__(256, 4) void k_tile(
    const float* __restrict__ X, const float* __restrict__ inb,
    const float* __restrict__ W, const float* __restrict__ b,
    float* __restrict__ Y, int N) {
  constexpr int KB = 32;
  constexpr int NCH = K / KB;
  __shared__ float xsT[KB][132];   // [k][row], pad keeps float4 alignment
  __shared__ float ws[KB][128];
  __shared__ float bs[128];
  __shared__ float inbs[K];
  for (int i = threadIdx.x; i < 128; i += 256) bs[i] = b[i];
  for (int i = threadIdx.x; i < K; i += 256) inbs[i] = inb ? inb[i] : 0.f;
  __syncthreads();
  int row0 = blockIdx.x * 128;
  int tx = threadIdx.x & 15, ty = threadIdx.x >> 4;
  float acc[8][8];
#pragma unroll
  for (int j = 0; j < 8; ++j) {
    float bj = bs[tx * 8 + j];
#pragma unroll
    for (int i = 0; i < 8; ++i) acc[i][j] = bj;
  }
  for (int ch = 0; ch < NCH; ++ch) {
    int k0 = ch * KB;
    // stage X^T chunk: lanes k-contiguous -> coalesced global reads
    for (int idx = threadIdx.x; idx < 128 * KB; idx += 256) {
      int k = idx & (KB - 1), r = idx >> 5;
      int row = row0 + r;
      float v = 0.f;
      if (row < N) {
        v = X[(size_t)row * K + k0 + k] + inbs[k0 + k];
        if (INRELU) v = fmaxf(v, 0.f);
      }
      xsT[k][r] = v;
    }
    // stage W chunk: linear, conflict-free
    for (int idx = threadIdx.x; idx < KB * 128; idx += 256) {
      int col = idx & 127, kk = idx >> 7;
      ws[kk][col] = W[(size_t)(k0 + kk) * 128 + col];
    }
    __syncthreads();
#pragma unroll 2
    for (int k = 0; k < KB; ++k) {
      float4 a0 = *(const float4*)&xsT[k][ty * 8];
      float4 a1 = *(const float4*)&xsT[k][ty * 8 + 4];
      float4 b0 = *(const float4*)&ws[k][tx * 8];
      float4 b1 = *(const float4*)&ws[k][tx * 8 + 4];
      float av[8] = {a0.x, a0.y, a0.z, a0.w, a1.x, a1.y, a1.z, a1.w};
      float bv[8] = {b0.x, b0.y, b0.z, b0.w, b1.x, b1.y, b1.z, b1.w};
#pragma unroll
      for (int i = 0; i < 8; ++i)
#pragma unroll
        for (int j = 0; j < 8; ++j) acc[i][j] += av[i] * bv[j];
    }
    __syncthreads();
  }
#pragma unroll
  for (int i = 0; i < 8; ++i) {
    int row = row0 + ty * 8 + i;
    if (row < N) {
      float o[8];
#pragma unroll
      for (int j = 0; j < 8; ++j) o[j] = OUTRELU ? fmaxf(acc[i][j], 0.f) : acc[i][j];
      float* yr = Y + (size_t)row * 128 + tx * 8;
      *(float4*)yr = make_float4(o[0], o[1], o[2], o[3]);
      *(float4*)(yr + 4) = make_float4(o[4], o[5], o[6], o[7]);
    }
  }
}

// =================== fused head: proj1 + classifier (K-chunked) ===================
// Phase1: Z = relu((X+inb)@W1+b1). Phase2 (re-stages X): S = sigmoid(relu((X+inb)@Wc1+bc1)@Wc2+bc2).
__global__ __launch_bounds__(256, 4) void k_head_fused(
    const float* __restrict__ X, const float* __restrict__ inb,
    const float* __restrict__ W1, const float* __restrict__ b1,
    const float* __restrict__ Wc1, const float* __restrict__ bc1,
    const float* __restrict__ Wc2, const float* __restrict__ bc2,
    float* __restrict__ Z, float* __restrict__ S, int N) {
  constexpr int KB = 32;
  __shared__ float xsT[KB][132];
  __shared__ float ws[KB * 128];
  __shared__ float bs[128];
  __shared__ float inbs[128];
  __shared__ float bs2[64];
  __shared__ float wc2s[64];
  for (int i = threadIdx.x; i < 128; i += 256) { bs[i] = b1[i]; inbs[i] = inb[i]; }
  if (threadIdx.x < 64) { bs2[threadIdx.x] = bc1[threadIdx.x]; wc2s[threadIdx.x] = Wc2[threadIdx.x]; }
  __syncthreads();
  int row0 = blockIdx.x * 128;
  int tx = threadIdx.x & 15, ty = threadIdx.x >> 4;
  // ---------- phase 1: proj1 ----------
  {
    float acc[8][8];
#pragma unroll
    for (int j = 0; j < 8; ++j) {
      float bj = bs[tx * 8 + j];
#pragma unroll
      for (int i = 0; i < 8; ++i) acc[i][j] = bj;
    }
    for (int ch = 0; ch < 4; ++ch) {
      int k0 = ch * KB;
      for (int idx = threadIdx.x; idx < 128 * KB; idx += 256) {
        int k = idx & 31, r = idx >> 5;
        int row = row0 + r;
        xsT[k][r] = (row < N) ? X[(size_t)row * 128 + k0 + k] + inbs[k0 + k] : 0.f;
      }
      for (int idx = threadIdx.x; idx < KB * 128; idx += 256) {
        int col = idx & 127, kk = idx >> 7;
        ws[kk * 128 + col] = W1[(size_t)(k0 + kk) * 128 + col];
      }
      __syncthreads();
#pragma unroll 2
      for (int k = 0; k < KB; ++k) {
        float4 a0 = *(const float4*)&xsT[k][ty * 8];
        float4 a1 = *(const float4*)&xsT[k][ty * 8 + 4];
        float4 b0 = *(const float4*)&ws[k * 128 + tx * 8];
        float4 b1 = *(const float4*)&ws[k * 128 + tx * 8 + 4];
        float av[8] = {a0.x, a0.y, a0.z, a0.w, a1.x, a1.y, a1.z, a1.w};
        float bv[8] = {b0.x, b0.y, b0.z, b0.w, b1.x, b1.y, b1.z, b1.w};
#pragma unroll
        for (int i = 0; i < 8; ++i)
#pragma unroll
          for (int j = 0; j < 8; ++j) acc[i][j] += av[i] * bv[j];
      }
      __syncthreads();
    }
#pragma unroll
    for (int i = 0; i < 8; ++i) {
      int row = row0 + ty * 8 + i;
      if (row < N) {
        float* zr = Z + (size_t)row * 128 + tx * 8;
        *(float4*)zr = make_float4(fmaxf(acc[i][0], 0.f), fmaxf(acc[i][1], 0.f),
                                   fmaxf(acc[i][2], 0.f), fmaxf(acc[i][3], 0.f));
        *(float4*)(zr + 4) = make_float4(fmaxf(acc[i][4], 0.f), fmaxf(acc[i][5], 0.f),
                                         fmaxf(acc[i][6], 0.f), fmaxf(acc[i][7], 0.f));
      }
    }
  }
  // ---------- phase 2: classifier ----------
  {
    float acc2[8][4];
#pragma unroll
    for (int j = 0; j < 4; ++j) {
      float bj = bs2[tx * 4 + j];
#pragma unroll
      for (int i = 0; i < 8; ++i) acc2[i][j] = bj;
    }
    for (int ch = 0; ch < 4; ++ch) {
      int k0 = ch * KB;
      __syncthreads();
      for (int idx = threadIdx.x; idx < 128 * KB; idx += 256) {
        int k = idx & 31, r = idx >> 5;
        int row = row0 + r;
        xsT[k][r] = (row < N) ? X[(size_t)row * 128 + k0 + k] + inbs[k0 + k] : 0.f;
      }
      for (int idx = threadIdx.x; idx < KB * 64; idx += 256) {
        int col = idx & 63, kk = idx >> 6;
        ws[kk * 64 + col] = Wc1[(size_t)(k0 + kk) * 64 + col];
      }
      __syncthreads();
#pragma unroll 2
      for (int k = 0; k < KB; ++k) {
        float4 a0 = *(const float4*)&xsT[k][ty * 8];
        float4 a1 = *(const float4*)&xsT[k][ty * 8 + 4];
        float4 w4 = *(const float4*)&ws[k * 64 + tx * 4];
        float av[8] = {a0.x, a0.y, a0.z, a0.w, a1.x, a1.y, a1.z, a1.w};
        float wv[4] = {w4.x, w4.y, w4.z, w4.w};
#pragma unroll
        for (int i = 0; i < 8; ++i)
#pragma unroll
          for (int j = 0; j < 4; ++j) acc2[i][j] += av[i] * wv[j];
      }
    }
    float w2a = wc2s[tx * 4], w2b = wc2s[tx * 4 + 1], w2c = wc2s[tx * 4 + 2], w2d = wc2s[tx * 4 + 3];
    float bb2 = bc2[0];
#pragma unroll
    for (int i = 0; i < 8; ++i) {
      float p = fmaxf(acc2[i][0], 0.f) * w2a + fmaxf(acc2[i][1], 0.f) * w2b +
                fmaxf(acc2[i][2], 0.f) * w2c + fmaxf(acc2[i][3], 0.f) * w2d;
      p += __shfl_xor(p, 1, 16);
      p += __shfl_xor(p, 2, 16);
      p += __shfl_xor(p, 4, 16);
      p += __shfl_xor(p, 8, 16);
      int row = row0 + ty * 8 + i;
      if (row < N && tx == 0) S[row] = 1.f / (1.f + __expf(-(p + bb2)));
    }
  }
}

// =================== CSR build (counting sort by key) ===================

__global__ __launch_bounds__(256) void k_hist(
    const int* __restrict__ key, int* __restrict__ hist, int E) {
  int e = blockIdx.x * 256 + threadIdx.x;
  if (e < E) atomicAdd(&hist[key[e]], 1);
}

#define SCAN_T 256
#define SCAN_V 4
#define SCAN_BLK 1024

__global__ __launch_bounds__(SCAN_T) void k_scan_local(
    const int* __restrict__ hist, int* __restrict__ starts,
    int* __restrict__ partials, int N) {
  __shared__ int sums[SCAN_T];
  int base = blockIdx.x * SCAN_BLK + threadIdx.x * SCAN_V;
  int v[SCAN_V];
  int s = 0;
#pragma unroll
  for (int i = 0; i < SCAN_V; ++i) { v[i] = (base + i < N) ? hist[base + i] : 0; s += v[i]; }
  sums[threadIdx.x] = s;
  __syncthreads();
  for (int off = 1; off < SCAN_T; off <<= 1) {
    int x = (threadIdx.x >= off) ? sums[threadIdx.x - off] : 0;
    __syncthreads();
    sums[threadIdx.x] += x;
    __syncthreads();
  }
  int run = (threadIdx.x > 0) ? sums[threadIdx.x - 1] : 0;
#pragma unroll
  for (int i = 0; i < SCAN_V; ++i) {
    if (base + i < N) starts[base + i] = run;
    run += v[i];
  }
  if (threadIdx.x == SCAN_T - 1) partials[blockIdx.x] = sums[SCAN_T - 1];
}

__global__ __launch_bounds__(SCAN_T) void k_scan_partials(int* partials, int nb) {
  __shared__ int s[SCAN_T];
  s[threadIdx.x] = (threadIdx.x < nb) ? partials[threadIdx.x] : 0;
  __syncthreads();
  for (int off = 1; off < SCAN_T; off <<= 1) {
    int x = (threadIdx.x >= off) ? s[threadIdx.x - off] : 0;
    __syncthreads();
    s[threadIdx.x] += x;
    __syncthreads();
  }
  if (threadIdx.x < nb) partials[threadIdx.x] = (threadIdx.x > 0) ? s[threadIdx.x - 1] : 0;
}

__global__ __launch_bounds__(256) void k_scan_add(
    int* __restrict__ starts, const int* __restrict__ partials,
    int* __restrict__ cursor, int N) {
  int i = blockIdx.x * 256 + threadIdx.x;
  if (i >= N) return;
  int v = starts[i] + partials[i / SCAN_BLK];
  starts[i] = v;
  cursor[i] = v;
}

__global__ __launch_bounds__(256) void k_scatter(
    const int* __restrict__ key, const int* __restrict__ other,
    int* __restrict__ cursor, int2* __restrict__ ebuf, int E) {
  int e = blockIdx.x * 256 + threadIdx.x;
  if (e >= E) return;
  int pos = atomicAdd(&cursor[key[e]], 1);
  ebuf[pos] = make_int2(other[e], e);
}

// =================== fused GATv2 edge phase ===================
template <int USE_EF>
__global__ __launch_bounds__(256) void k_gat(
    const float* __restrict__ xl, const float* __restrict__ xr,
    const int2* __restrict__ ebuf, const int* __restrict__ starts,
    const int* __restrict__ counts, const float* __restrict__ att,
    const float* __restrict__ eattr, const float* __restrict__ We,
    float* __restrict__ agg, int N) {
  int wid = (blockIdx.x * 256 + threadIdx.x) >> 6;
  if (wid >= N) return;
  int lane = threadIdx.x & 63;
  int g = lane >> 4;
  int t = lane & 15;
  int c = g * 32 + t * 2;
  float att0 = att[c], att1 = att[c + 1];
  float2 we0, we1, we2;
  if (USE_EF) {
    we0 = *(const float2*)(We + 0 * HC + c);
    we1 = *(const float2*)(We + 1 * HC + c);
    we2 = *(const float2*)(We + 2 * HC + c);
  }
  float2 xrv = *(const float2*)(xr + (size_t)wid * HC + c);
  int st = starts[wid], cnt = counts[wid];
  float m = -3.402823466e38f, dsum = 0.f, a0 = 0.f, a1 = 0.f;
  for (int i = 0; i < cnt; ++i) {
    int2 se = ebuf[st + i];
    float2 xlv = *(const float2*)(xl + (size_t)se.x * HC + c);
    float x0 = xlv.x + xrv.x, x1 = xlv.y + xrv.y;
    if (USE_EF) {
      const float* ea = eattr + (size_t)se.y * 3;
      float e0 = ea[0], e1 = ea[1], e2 = ea[2];
      x0 += e0 * we0.x + e1 * we1.x + e2 * we2.x;
      x1 += e0 * we0.y + e1 * we1.y + e2 * we2.y;
    }
    x0 = (x0 > 0.f) ? x0 : 0.2f * x0;
    x1 = (x1 > 0.f) ? x1 : 0.2f * x1;
    float p = x0 * att0 + x1 * att1;
    p += __shfl_xor(p, 1, 16);
    p += __shfl_xor(p, 2, 16);
    p += __shfl_xor(p, 4, 16);
    p += __shfl_xor(p, 8, 16);
    float newm = fmaxf(m, p);
    float scale = __expf(m - newm);
    float w = __expf(p - newm);
    dsum = dsum * scale + w;
    a0 = a0 * scale + w * xlv.x;
    a1 = a1 * scale + w * xlv.y;
    m = newm;
  }
  float inv = (dsum > 0.f) ? 1.f / dsum : 0.f;
  *(float2*)(agg + (size_t)wid * HC + c) = make_float2(a0 * inv, a1 * inv);
}

static inline int imin(int a, int b) { return a < b ? a : b; }

extern "C" void kernel_launch(void* const* d_in, const int* in_sizes, int n_in,
                              void* d_out, int out_size, void* d_ws, size_t ws_size,
                              hipStream_t stream) {
  const float* customer_x = (const float*)d_in[0];
  const float* fund_x     = (const float*)d_in[1];
  const int*   edge_src   = (const int*)d_in[2];
  const int*   edge_dst   = (const int*)d_in[3];
  const float* edge_attr  = (const float*)d_in[4];
  const float* user_W = (const float*)d_in[5];
  const float* user_b = (const float*)d_in[6];
  const float* item_W = (const float*)d_in[7];
  const float* item_b = (const float*)d_in[8];
  const float* c1_Wl = (const float*)d_in[9];
  const float* c1_bl = (const float*)d_in[10];
  const float* c1_Wr = (const float*)d_in[11];
  const float* c1_br = (const float*)d_in[12];
  const float* c1_att = (const float*)d_in[13];
  const float* c1_We  = (const float*)d_in[14];
  const float* c1_bias = (const float*)d_in[15];
  const float* c2_Wl = (const float*)d_in[16];
  const float* c2_bl = (const float*)d_in[17];
  const float* c2_Wr = (const float*)d_in[18];
  const float* c2_br = (const float*)d_in[19];
  const float* c2_att = (const float*)d_in[20];
  const float* c2_bias = (const float*)d_in[21];
  const float* proj_W1 = (const float*)d_in[22];
  const float* proj_b1 = (const float*)d_in[23];
  const float* proj_W2 = (const float*)d_in[24];
  const float* proj_b2 = (const float*)d_in[25];
  const float* cls_W1 = (const float*)d_in[26];
  const float* cls_b1 = (const float*)d_in[27];
  const float* cls_W2 = (const float*)d_in[28];
  const float* cls_b2 = (const float*)d_in[29];

  const int Ncust = in_sizes[0] / 101;
  const int Nitem = in_sizes[1];
  const int E     = in_sizes[2];

  // -------- workspace layout (~148 MiB) --------
  float* w = (float*)d_ws;
  float* user_x  = w; w += (size_t)Ncust * 32;
  float* item_x0 = w; w += (size_t)Nitem * 32;
  float* bufC    = w; w += (size_t)Ncust * HC;   // xl1 -> xr2 -> proj1 out
  float* bufD    = w; w += (size_t)Nitem * HC;   // xr1 -> xl2
  float* agg1    = w; w += (size_t)Nitem * HC;
  float* agg2    = w; w += (size_t)Ncust * HC;
  int* hist1   = (int*)w; w += Nitem;
  int* starts1 = (int*)w; w += Nitem;
  int* cursor1 = (int*)w; w += Nitem;
  int* hist2   = (int*)w; w += Ncust;
  int* starts2 = (int*)w; w += Ncust;
  int* cursor2 = (int*)w; w += Ncust;
  int* partials = (int*)w; w += 512;
  int2* ebuf1 = (int2*)w; w += (size_t)E * 2;
  int2* ebuf2 = (int2*)w; w += (size_t)E * 2;
  if ((size_t)((char*)w - (char*)d_ws) > ws_size) return;

  float* out_scores = (float*)d_out;
  float* out_z      = out_scores + Ncust;

  const int egrid = (E + 255) / 256;
  const int nb1 = (Nitem + SCAN_BLK - 1) / SCAN_BLK;
  const int nb2 = (Ncust + SCAN_BLK - 1) / SCAN_BLK;
  const int nt1 = (Ncust + 127) / 128;
  const int nt2 = (Nitem + 127) / 128;

  // -------- CSR build --------
  hipMemsetAsync(hist1, 0, (size_t)Nitem * 4, stream);
  hipMemsetAsync(hist2, 0, (size_t)Ncust * 4, stream);
  k_hist<<<egrid, 256, 0, stream>>>(edge_dst, hist1, E);
  k_hist<<<egrid, 256, 0, stream>>>(edge_src, hist2, E);
  k_scan_local<<<nb1, SCAN_T, 0, stream>>>(hist1, starts1, partials, Nitem);
  k_scan_partials<<<1, SCAN_T, 0, stream>>>(partials, nb1);
  k_scan_add<<<(Nitem + 255) / 256, 256, 0, stream>>>(starts1, partials, cursor1, Nitem);
  k_scatter<<<egrid, 256, 0, stream>>>(edge_dst, edge_src, cursor1, ebuf1, E);
  k_scan_local<<<nb2, SCAN_T, 0, stream>>>(hist2, starts2, partials, Ncust);
  k_scan_partials<<<1, SCAN_T, 0, stream>>>(partials, nb2);
  k_scan_add<<<(Ncust + 255) / 256, 256, 0, stream>>>(starts2, partials, cursor2, Ncust);
  k_scatter<<<egrid, 256, 0, stream>>>(edge_src, edge_dst, cursor2, ebuf2, E);

  // -------- node projections --------
  k_proj101<<<(Ncust + 255) / 256, 256, 0, stream>>>(customer_x, user_W, user_b, user_x, Ncust);
  k_item_proj<<<(Nitem * 32 + 255) / 256, 256, 0, stream>>>(fund_x, item_W, item_b, item_x0, Nitem);

  // -------- conv1 (customer -> fund, edge features) --------
  k_tile<32, 0, 0><<<nt1, 256, 0, stream>>>(user_x, nullptr, c1_Wl, c1_bl, bufC, Ncust);
  k_tile<32, 0, 0><<<nt2, 256, 0, stream>>>(item_x0, nullptr, c1_Wr, c1_br, bufD, Nitem);
  k_gat<1><<<(Nitem + 3) / 4, 256, 0, stream>>>(bufC, bufD, ebuf1, starts1, hist1,
                                                c1_att, edge_attr, c1_We, agg1, Nitem);

  // -------- conv2 (fund -> customer, flipped edges) --------
  k_tile<128, 1, 0><<<nt2, 256, 0, stream>>>(agg1, c1_bias, c2_Wl, c2_bl, bufD, Nitem);
  k_tile<32, 0, 0><<<nt1, 256, 0, stream>>>(user_x, nullptr, c2_Wr, c2_br, bufC, Ncust);
  k_gat<0><<<(Ncust + 3) / 4, 256, 0, stream>>>(bufD, bufC, ebuf2, starts2, hist2,
                                                c2_att, nullptr, nullptr, agg2, Ncust);

  // -------- heads --------
  k_head_fused<<<nt1, 256, 0, stream>>>(agg2, c2_bias, proj_W1, proj_b1,
                                        cls_W1, cls_b1, cls_W2, cls_b2,
                                        bufC, out_scores, Ncust);
  k_tile<128, 0, 0><<<nt1, 256, 0, stream>>>(bufC, nullptr, proj_W2, proj_b2, out_z, Ncust);
}

// Round 6
// 521.901 us; speedup vs baseline: 14.7447x; 1.2255x over previous
//
#include <hip/hip_runtime.h>
#include <math.h>

#define HH 4
#define CC 32
#define HC 128

__device__ __forceinline__ float relu4x(float v) { return fmaxf(v, 0.f); }

// =================== node projection: customer_x[101] -> user_x[32] ===================
// 64 rows/block, LDS-staged with coalesced float4 loads.
__global__ __launch_bounds__(256) void k_proj101(
    const float* __restrict__ X, const float* __restrict__ W,
    const float* __restrict__ b, float* __restrict__ Y, int N) {
  __shared__ float xs[64][105];    // pad 105: banks (r*9+k)%32 -> conflict-free
  __shared__ float Ws[101 * 32];
  __shared__ float bs[32];
  for (int i = threadIdx.x; i < 101 * 32; i += 256) Ws[i] = W[i];
  if (threadIdx.x < 32) bs[threadIdx.x] = b[threadIdx.x];
  int row0 = blockIdx.x * 64;
  // stage 64 rows: 25 float4 + 1 scalar each
  for (int idx = threadIdx.x; idx < 64 * 25; idx += 256) {
    int f = idx % 25, r = idx / 25;
    int row = row0 + r;
    float4 v = make_float4(0.f, 0.f, 0.f, 0.f);
    if (row < N) v = *(const float4*)(X + (size_t)row * 101 + f * 4);
    xs[r][f * 4 + 0] = v.x; xs[r][f * 4 + 1] = v.y;
    xs[r][f * 4 + 2] = v.z; xs[r][f * 4 + 3] = v.w;
  }
  if (threadIdx.x < 64) {
    int row = row0 + threadIdx.x;
    xs[threadIdx.x][100] = (row < N) ? X[(size_t)row * 101 + 100] : 0.f;
  }
  __syncthreads();
  int q = threadIdx.x & 3;          // col group (8 cols)
  int r = threadIdx.x >> 2;         // row 0..63
  float acc[8];
#pragma unroll
  for (int j = 0; j < 8; ++j) acc[j] = bs[q * 8 + j];
  for (int k = 0; k < 101; ++k) {
    float xv = xs[r][k];
    float4 w0 = *(const float4*)&Ws[k * 32 + q * 8];
    float4 w1 = *(const float4*)&Ws[k * 32 + q * 8 + 4];
    acc[0] += xv * w0.x; acc[1] += xv * w0.y; acc[2] += xv * w0.z; acc[3] += xv * w0.w;
    acc[4] += xv * w1.x; acc[5] += xv * w1.y; acc[6] += xv * w1.z; acc[7] += xv * w1.w;
  }
  int row = row0 + r;
  if (row < N) {
    float* yr = Y + (size_t)row * 32 + q * 8;
    *(float4*)yr = make_float4(acc[0], acc[1], acc[2], acc[3]);
    *(float4*)(yr + 4) = make_float4(acc[4], acc[5], acc[6], acc[7]);
  }
}

__global__ __launch_bounds__(256) void k_item_proj(
    const float* __restrict__ X, const float* __restrict__ W,
    const float* __restrict__ b, float* __restrict__ Y, int N) {
  int t = blockIdx.x * 256 + threadIdx.x;
  if (t >= N * 32) return;
  int i = t >> 5, c = t & 31;
  Y[t] = X[i] * W[c] + b[c];
}

// =================== K-chunked tiled GEMM (8x8 micro-tile, float4 staging) ===================
template <int K, int INRELU, int OUTRELU>
__global__ __launch_bounds__(256, 4) void k_tile(
    const float* __restrict__ X, const float* __restrict__ inb,
    const float* __restrict__ W, const float* __restrict__ b,
    float* __restrict__ Y, int N) {
  constexpr int KB = 32;
  constexpr int NCH = K / KB;
  __shared__ float xsT[KB][132];
  __shared__ float ws[KB][128];
  __shared__ float bs[128];
  __shared__ float inbs[K];
  for (int i = threadIdx.x; i < 128; i += 256) bs[i] = b[i];
  for (int i = threadIdx.x; i < K; i += 256) inbs[i] = inb ? inb[i] : 0.f;
  __syncthreads();
  int row0 = blockIdx.x * 128;
  int tx = threadIdx.x & 15, ty = threadIdx.x >> 4;
  float acc[8][8];
#pragma unroll
  for (int j = 0; j < 8; ++j) {
    float bj = bs[tx * 8 + j];
#pragma unroll
    for (int i = 0; i < 8; ++i) acc[i][j] = bj;
  }
  for (int ch = 0; ch < NCH; ++ch) {
    int k0 = ch * KB;
    // X chunk: float4 along k, transposed scalar LDS writes
    for (int idx = threadIdx.x; idx < 128 * 8; idx += 256) {
      int f = idx & 7, r = idx >> 3;
      int row = row0 + r;
      float4 v = make_float4(0.f, 0.f, 0.f, 0.f);
      if (row < N) {
        v = *(const float4*)(X + (size_t)row * K + k0 + f * 4);
        v.x += inbs[k0 + f * 4 + 0]; v.y += inbs[k0 + f * 4 + 1];
        v.z += inbs[k0 + f * 4 + 2]; v.w += inbs[k0 + f * 4 + 3];
        if (INRELU) { v.x = relu4x(v.x); v.y = relu4x(v.y); v.z = relu4x(v.z); v.w = relu4x(v.w); }
      }
      xsT[f * 4 + 0][r] = v.x; xsT[f * 4 + 1][r] = v.y;
      xsT[f * 4 + 2][r] = v.z; xsT[f * 4 + 3][r] = v.w;
    }
    // W chunk: float4 linear
    for (int idx = threadIdx.x; idx < KB * 32; idx += 256) {
      int c4 = (idx & 31) * 4, kk = idx >> 5;
      *(float4*)&ws[kk][c4] = *(const float4*)(W + (size_t)(k0 + kk) * 128 + c4);
    }
    __syncthreads();
#pragma unroll 2
    for (int k = 0; k < KB; ++k) {
      float4 a0 = *(const float4*)&xsT[k][ty * 8];
      float4 a1 = *(const float4*)&xsT[k][ty * 8 + 4];
      float4 b0 = *(const float4*)&ws[k][tx * 8];
      float4 b1 = *(const float4*)&ws[k][tx * 8 + 4];
      float av[8] = {a0.x, a0.y, a0.z, a0.w, a1.x, a1.y, a1.z, a1.w};
      float bv[8] = {b0.x, b0.y, b0.z, b0.w, b1.x, b1.y, b1.z, b1.w};
#pragma unroll
      for (int i = 0; i < 8; ++i)
#pragma unroll
        for (int j = 0; j < 8; ++j) acc[i][j] += av[i] * bv[j];
    }
    __syncthreads();
  }
#pragma unroll
  for (int i = 0; i < 8; ++i) {
    int row = row0 + ty * 8 + i;
    if (row < N) {
      float o[8];
#pragma unroll
      for (int j = 0; j < 8; ++j) o[j] = OUTRELU ? fmaxf(acc[i][j], 0.f) : acc[i][j];
      float* yr = Y + (size_t)row * 128 + tx * 8;
      *(float4*)yr = make_float4(o[0], o[1], o[2], o[3]);
      *(float4*)(yr + 4) = make_float4(o[4], o[5], o[6], o[7]);
    }
  }
}

// =================== dual K=32 GEMM: Y1 = X@W1+b1, Y2 = X@W2+b2 ===================
__global__ __launch_bounds__(256, 3) void k_dual32(
    const float* __restrict__ X,
    const float* __restrict__ W1, const float* __restrict__ b1,
    const float* __restrict__ W2, const float* __restrict__ b2,
    float* __restrict__ Y1, float* __restrict__ Y2, int N) {
  __shared__ float xsT[32][132];
  __shared__ float ws1[32][128];
  __shared__ float ws2[32][128];
  __shared__ float bs1[128];
  __shared__ float bs2[128];
  for (int i = threadIdx.x; i < 128; i += 256) { bs1[i] = b1[i]; bs2[i] = b2[i]; }
  int row0 = blockIdx.x * 128;
  for (int idx = threadIdx.x; idx < 128 * 8; idx += 256) {
    int f = idx & 7, r = idx >> 3;
    int row = row0 + r;
    float4 v = make_float4(0.f, 0.f, 0.f, 0.f);
    if (row < N) v = *(const float4*)(X + (size_t)row * 32 + f * 4);
    xsT[f * 4 + 0][r] = v.x; xsT[f * 4 + 1][r] = v.y;
    xsT[f * 4 + 2][r] = v.z; xsT[f * 4 + 3][r] = v.w;
  }
  for (int idx = threadIdx.x; idx < 32 * 32; idx += 256) {
    int c4 = (idx & 31) * 4, kk = idx >> 5;
    *(float4*)&ws1[kk][c4] = *(const float4*)(W1 + (size_t)kk * 128 + c4);
    *(float4*)&ws2[kk][c4] = *(const float4*)(W2 + (size_t)kk * 128 + c4);
  }
  __syncthreads();
  int tx = threadIdx.x & 15, ty = threadIdx.x >> 4;
  float acc1[8][8], acc2[8][8];
#pragma unroll
  for (int j = 0; j < 8; ++j) {
    float c1 = bs1[tx * 8 + j], c2 = bs2[tx * 8 + j];
#pragma unroll
    for (int i = 0; i < 8; ++i) { acc1[i][j] = c1; acc2[i][j] = c2; }
  }
#pragma unroll 2
  for (int k = 0; k < 32; ++k) {
    float4 a0 = *(const float4*)&xsT[k][ty * 8];
    float4 a1 = *(const float4*)&xsT[k][ty * 8 + 4];
    float4 p0 = *(const float4*)&ws1[k][tx * 8];
    float4 p1 = *(const float4*)&ws1[k][tx * 8 + 4];
    float4 q0 = *(const float4*)&ws2[k][tx * 8];
    float4 q1 = *(const float4*)&ws2[k][tx * 8 + 4];
    float av[8] = {a0.x, a0.y, a0.z, a0.w, a1.x, a1.y, a1.z, a1.w};
    float pv[8] = {p0.x, p0.y, p0.z, p0.w, p1.x, p1.y, p1.z, p1.w};
    float qv[8] = {q0.x, q0.y, q0.z, q0.w, q1.x, q1.y, q1.z, q1.w};
#pragma unroll
    for (int i = 0; i < 8; ++i)
#pragma unroll
      for (int j = 0; j < 8; ++j) { acc1[i][j] += av[i] * pv[j]; acc2[i][j] += av[i] * qv[j]; }
  }
#pragma unroll
  for (int i = 0; i < 8; ++i) {
    int row = row0 + ty * 8 + i;
    if (row < N) {
      float* y1 = Y1 + (size_t)row * 128 + tx * 8;
      float* y2 = Y2 + (size_t)row * 128 + tx * 8;
      *(float4*)y1 = make_float4(acc1[i][0], acc1[i][1], acc1[i][2], acc1[i][3]);
      *(float4*)(y1 + 4) = make_float4(acc1[i][4], acc1[i][5], acc1[i][6], acc1[i][7]);
      *(float4*)y2 = make_float4(acc2[i][0], acc2[i][1], acc2[i][2], acc2[i][3]);
      *(float4*)(y2 + 4) = make_float4(acc2[i][4], acc2[i][5], acc2[i][6], acc2[i][7]);
    }
  }
}

// =================== fully fused head ===================
// X = agg2+inb (one pass). Main loop: acc=X@W1+b1 (proj1), accc=X@Wc1+bc1 (cls1).
// Epilogue: S = sigmoid(relu(accc)@Wc2+bc2). Phase C: out_z = relu(acc)@W2+b2
// via in-LDS register transpose of acc (z1 never hits global).
__global__ __launch_bounds__(256, 3) void k_head_fused(
    const float* __restrict__ X, const float* __restrict__ inb,
    const float* __restrict__ W1, const float* __restrict__ b1,
    const float* __restrict__ W2, const float* __restrict__ b2,
    const float* __restrict__ Wc1, const float* __restrict__ bc1,
    const float* __restrict__ Wc2, const float* __restrict__ bc2,
    float* __restrict__ Z, float* __restrict__ S, int N) {
  __shared__ float xsT[32][132];
  __shared__ float ws[32][128];
  __shared__ float ws2[32][64];
  __shared__ float bs[128];
  __shared__ float inbs[128];
  __shared__ float bsc[64];
  __shared__ float wc2s[64];
  for (int i = threadIdx.x; i < 128; i += 256) { bs[i] = b1[i]; inbs[i] = inb[i]; }
  if (threadIdx.x < 64) { bsc[threadIdx.x] = bc1[threadIdx.x]; wc2s[threadIdx.x] = Wc2[threadIdx.x]; }
  __syncthreads();
  int row0 = blockIdx.x * 128;
  int tx = threadIdx.x & 15, ty = threadIdx.x >> 4;
  float acc[8][8], accc[8][4];
#pragma unroll
  for (int j = 0; j < 8; ++j) {
    float bj = bs[tx * 8 + j];
#pragma unroll
    for (int i = 0; i < 8; ++i) acc[i][j] = bj;
  }
#pragma unroll
  for (int j = 0; j < 4; ++j) {
    float bj = bsc[tx * 4 + j];
#pragma unroll
    for (int i = 0; i < 8; ++i) accc[i][j] = bj;
  }
  // -------- main loop: single X pass feeds proj1 + cls1 --------
  for (int ch = 0; ch < 4; ++ch) {
    int k0 = ch * 32;
    for (int idx = threadIdx.x; idx < 128 * 8; idx += 256) {
      int f = idx & 7, r = idx >> 3;
      int row = row0 + r;
      float4 v = make_float4(0.f, 0.f, 0.f, 0.f);
      if (row < N) {
        v = *(const float4*)(X + (size_t)row * 128 + k0 + f * 4);
        v.x += inbs[k0 + f * 4 + 0]; v.y += inbs[k0 + f * 4 + 1];
        v.z += inbs[k0 + f * 4 + 2]; v.w += inbs[k0 + f * 4 + 3];
      }
      xsT[f * 4 + 0][r] = v.x; xsT[f * 4 + 1][r] = v.y;
      xsT[f * 4 + 2][r] = v.z; xsT[f * 4 + 3][r] = v.w;
    }
    for (int idx = threadIdx.x; idx < 32 * 32; idx += 256) {
      int c4 = (idx & 31) * 4, kk = idx >> 5;
      *(float4*)&ws[kk][c4] = *(const float4*)(W1 + (size_t)(k0 + kk) * 128 + c4);
    }
    for (int idx = threadIdx.x; idx < 32 * 16; idx += 256) {
      int c4 = (idx & 15) * 4, kk = idx >> 4;
      *(float4*)&ws2[kk][c4] = *(const float4*)(Wc1 + (size_t)(k0 + kk) * 64 + c4);
    }
    __syncthreads();
#pragma unroll 2
    for (int k = 0; k < 32; ++k) {
      float4 a0 = *(const float4*)&xsT[k][ty * 8];
      float4 a1 = *(const float4*)&xsT[k][ty * 8 + 4];
      float4 b0 = *(const float4*)&ws[k][tx * 8];
      float4 b1v = *(const float4*)&ws[k][tx * 8 + 4];
      float4 cv = *(const float4*)&ws2[k][tx * 4];
      float av[8] = {a0.x, a0.y, a0.z, a0.w, a1.x, a1.y, a1.z, a1.w};
      float bv[8] = {b0.x, b0.y, b0.z, b0.w, b1v.x, b1v.y, b1v.z, b1v.w};
      float cw[4] = {cv.x, cv.y, cv.z, cv.w};
#pragma unroll
      for (int i = 0; i < 8; ++i) {
#pragma unroll
        for (int j = 0; j < 8; ++j) acc[i][j] += av[i] * bv[j];
#pragma unroll
        for (int j = 0; j < 4; ++j) accc[i][j] += av[i] * cw[j];
      }
    }
    __syncthreads();
  }
  // -------- cls epilogue: S --------
  {
    float w2a = wc2s[tx * 4], w2b = wc2s[tx * 4 + 1], w2c = wc2s[tx * 4 + 2], w2d = wc2s[tx * 4 + 3];
    float bb2 = bc2[0];
#pragma unroll
    for (int i = 0; i < 8; ++i) {
      float p = fmaxf(accc[i][0], 0.f) * w2a + fmaxf(accc[i][1], 0.f) * w2b +
                fmaxf(accc[i][2], 0.f) * w2c + fmaxf(accc[i][3], 0.f) * w2d;
      p += __shfl_xor(p, 1, 16);
      p += __shfl_xor(p, 2, 16);
      p += __shfl_xor(p, 4, 16);
      p += __shfl_xor(p, 8, 16);
      int row = row0 + ty * 8 + i;
      if (row < N && tx == 0) S[row] = 1.f / (1.f + __expf(-(p + bb2)));
    }
  }
  // -------- phase C: out_z = relu(z1) @ W2 + b2, z1 from acc via LDS transpose --------
  float acc3[8][8];
#pragma unroll
  for (int j = 0; j < 8; ++j) {
    float bj = b2[tx * 8 + j];
#pragma unroll
    for (int i = 0; i < 8; ++i) acc3[i][j] = bj;
  }
  for (int ch = 0; ch < 4; ++ch) {
    // z1 cols [ch*32, ch*32+32) live in threads with tx>>2 == ch
    if ((tx >> 2) == ch) {
#pragma unroll
      for (int j = 0; j < 8; ++j) {
        int colk = (tx & 3) * 8 + j;
        *(float4*)&xsT[colk][ty * 8] =
            make_float4(fmaxf(acc[0][j], 0.f), fmaxf(acc[1][j], 0.f),
                        fmaxf(acc[2][j], 0.f), fmaxf(acc[3][j], 0.f));
        *(float4*)&xsT[colk][ty * 8 + 4] =
            make_float4(fmaxf(acc[4][j], 0.f), fmaxf(acc[5][j], 0.f),
                        fmaxf(acc[6][j], 0.f), fmaxf(acc[7][j], 0.f));
      }
    }
    for (int idx = threadIdx.x; idx < 32 * 32; idx += 256) {
      int c4 = (idx & 31) * 4, kk = idx >> 5;
      *(float4*)&ws[kk][c4] = *(const float4*)(W2 + (size_t)(ch * 32 + kk) * 128 + c4);
    }
    __syncthreads();
#pragma unroll 2
    for (int k = 0; k < 32; ++k) {
      float4 a0 = *(const float4*)&xsT[k][ty * 8];
      float4 a1 = *(const float4*)&xsT[k][ty * 8 + 4];
      float4 b0 = *(const float4*)&ws[k][tx * 8];
      float4 b1v = *(const float4*)&ws[k][tx * 8 + 4];
      float av[8] = {a0.x, a0.y, a0.z, a0.w, a1.x, a1.y, a1.z, a1.w};
      float bv[8] = {b0.x, b0.y, b0.z, b0.w, b1v.x, b1v.y, b1v.z, b1v.w};
#pragma unroll
      for (int i = 0; i < 8; ++i)
#pragma unroll
        for (int j = 0; j < 8; ++j) acc3[i][j] += av[i] * bv[j];
    }
    __syncthreads();
  }
#pragma unroll
  for (int i = 0; i < 8; ++i) {
    int row = row0 + ty * 8 + i;
    if (row < N) {
      float* zr = Z + (size_t)row * 128 + tx * 8;
      *(float4*)zr = make_float4(acc3[i][0], acc3[i][1], acc3[i][2], acc3[i][3]);
      *(float4*)(zr + 4) = make_float4(acc3[i][4], acc3[i][5], acc3[i][6], acc3[i][7]);
    }
  }
}

// =================== CSR build (counting sort by key) ===================

__global__ __launch_bounds__(256) void k_hist(
    const int* __restrict__ key, int* __restrict__ hist, int E) {
  int e = blockIdx.x * 256 + threadIdx.x;
  if (e < E) atomicAdd(&hist[key[e]], 1);
}

#define SCAN_T 256
#define SCAN_V 4
#define SCAN_BLK 1024

__global__ __launch_bounds__(SCAN_T) void k_scan_local(
    const int* __restrict__ hist, int* __restrict__ starts,
    int* __restrict__ partials, int N) {
  __shared__ int sums[SCAN_T];
  int base = blockIdx.x * SCAN_BLK + threadIdx.x * SCAN_V;
  int v[SCAN_V];
  int s = 0;
#pragma unroll
  for (int i = 0; i < SCAN_V; ++i) { v[i] = (base + i < N) ? hist[base + i] : 0; s += v[i]; }
  sums[threadIdx.x] = s;
  __syncthreads();
  for (int off = 1; off < SCAN_T; off <<= 1) {
    int x = (threadIdx.x >= off) ? sums[threadIdx.x - off] : 0;
    __syncthreads();
    sums[threadIdx.x] += x;
    __syncthreads();
  }
  int run = (threadIdx.x > 0) ? sums[threadIdx.x - 1] : 0;
#pragma unroll
  for (int i = 0; i < SCAN_V; ++i) {
    if (base + i < N) starts[base + i] = run;
    run += v[i];
  }
  if (threadIdx.x == SCAN_T - 1) partials[blockIdx.x] = sums[SCAN_T - 1];
}

__global__ __launch_bounds__(SCAN_T) void k_scan_partials(int* partials, int nb) {
  __shared__ int s[SCAN_T];
  s[threadIdx.x] = (threadIdx.x < nb) ? partials[threadIdx.x] : 0;
  __syncthreads();
  for (int off = 1; off < SCAN_T; off <<= 1) {
    int x = (threadIdx.x >= off) ? s[threadIdx.x - off] : 0;
    __syncthreads();
    s[threadIdx.x] += x;
    __syncthreads();
  }
  if (threadIdx.x < nb) partials[threadIdx.x] = (threadIdx.x > 0) ? s[threadIdx.x - 1] : 0;
}

__global__ __launch_bounds__(256) void k_scan_add(
    int* __restrict__ starts, const int* __restrict__ partials,
    int* __restrict__ cursor, int N) {
  int i = blockIdx.x * 256 + threadIdx.x;
  if (i >= N) return;
  int v = starts[i] + partials[i / SCAN_BLK];
  starts[i] = v;
  cursor[i] = v;
}

__global__ __launch_bounds__(256) void k_scatter(
    const int* __restrict__ key, const int* __restrict__ other,
    int* __restrict__ cursor, int2* __restrict__ ebuf, int E) {
  int e = blockIdx.x * 256 + threadIdx.x;
  if (e >= E) return;
  int pos = atomicAdd(&cursor[key[e]], 1);
  ebuf[pos] = make_int2(other[e], e);
}

// =================== fused GATv2 edge phase (gather-only, online softmax) ===================
// In-place safe: xr may alias agg (each lane reads its xr element before writing agg).
template <int USE_EF>
__global__ __launch_bounds__(256) void k_gat(
    const float* __restrict__ xl, const float* __restrict__ xr,
    const int2* __restrict__ ebuf, const int* __restrict__ starts,
    const int* __restrict__ counts, const float* __restrict__ att,
    const float* __restrict__ eattr, const float* __restrict__ We,
    float* __restrict__ agg, int N) {
  int wid = (blockIdx.x * 256 + threadIdx.x) >> 6;
  if (wid >= N) return;
  int lane = threadIdx.x & 63;
  int g = lane >> 4;
  int t = lane & 15;
  int c = g * 32 + t * 2;
  float att0 = att[c], att1 = att[c + 1];
  float2 we0, we1, we2;
  if (USE_EF) {
    we0 = *(const float2*)(We + 0 * HC + c);
    we1 = *(const float2*)(We + 1 * HC + c);
    we2 = *(const float2*)(We + 2 * HC + c);
  }
  float2 xrv = *(const float2*)(xr + (size_t)wid * HC + c);
  int st = starts[wid], cnt = counts[wid];
  float m = -3.402823466e38f, dsum = 0.f, a0 = 0.f, a1 = 0.f;
  for (int i = 0; i < cnt; ++i) {
    int2 se = ebuf[st + i];
    float2 xlv = *(const float2*)(xl + (size_t)se.x * HC + c);
    float x0 = xlv.x + xrv.x, x1 = xlv.y + xrv.y;
    if (USE_EF) {
      const float* ea = eattr + (size_t)se.y * 3;
      float e0 = ea[0], e1 = ea[1], e2 = ea[2];
      x0 += e0 * we0.x + e1 * we1.x + e2 * we2.x;
      x1 += e0 * we0.y + e1 * we1.y + e2 * we2.y;
    }
    x0 = (x0 > 0.f) ? x0 : 0.2f * x0;
    x1 = (x1 > 0.f) ? x1 : 0.2f * x1;
    float p = x0 * att0 + x1 * att1;
    p += __shfl_xor(p, 1, 16);
    p += __shfl_xor(p, 2, 16);
    p += __shfl_xor(p, 4, 16);
    p += __shfl_xor(p, 8, 16);
    float newm = fmaxf(m, p);
    float scale = __expf(m - newm);
    float w = __expf(p - newm);
    dsum = dsum * scale + w;
    a0 = a0 * scale + w * xlv.x;
    a1 = a1 * scale + w * xlv.y;
    m = newm;
  }
  float inv = (dsum > 0.f) ? 1.f / dsum : 0.f;
  *(float2*)(agg + (size_t)wid * HC + c) = make_float2(a0 * inv, a1 * inv);
}

static inline int imin(int a, int b) { return a < b ? a : b; }

extern "C" void kernel_launch(void* const* d_in, const int* in_sizes, int n_in,
                              void* d_out, int out_size, void* d_ws, size_t ws_size,
                              hipStream_t stream) {
  const float* customer_x = (const float*)d_in[0];
  const float* fund_x     = (const float*)d_in[1];
  const int*   edge_src   = (const int*)d_in[2];
  const int*   edge_dst   = (const int*)d_in[3];
  const float* edge_attr  = (const float*)d_in[4];
  const float* user_W = (const float*)d_in[5];
  const float* user_b = (const float*)d_in[6];
  const float* item_W = (const float*)d_in[7];
  const float* item_b = (const float*)d_in[8];
  const float* c1_Wl = (const float*)d_in[9];
  const float* c1_bl = (const float*)d_in[10];
  const float* c1_Wr = (const float*)d_in[11];
  const float* c1_br = (const float*)d_in[12];
  const float* c1_att = (const float*)d_in[13];
  const float* c1_We  = (const float*)d_in[14];
  const float* c1_bias = (const float*)d_in[15];
  const float* c2_Wl = (const float*)d_in[16];
  const float* c2_bl = (const float*)d_in[17];
  const float* c2_Wr = (const float*)d_in[18];
  const float* c2_br = (const float*)d_in[19];
  const float* c2_att = (const float*)d_in[20];
  const float* c2_bias = (const float*)d_in[21];
  const float* proj_W1 = (const float*)d_in[22];
  const float* proj_b1 = (const float*)d_in[23];
  const float* proj_W2 = (const float*)d_in[24];
  const float* proj_b2 = (const float*)d_in[25];
  const float* cls_W1 = (const float*)d_in[26];
  const float* cls_b1 = (const float*)d_in[27];
  const float* cls_W2 = (const float*)d_in[28];
  const float* cls_b2 = (const float*)d_in[29];

  const int Ncust = in_sizes[0] / 101;
  const int Nitem = in_sizes[1];
  const int E     = in_sizes[2];

  // -------- workspace layout (~141 MiB) --------
  float* w = (float*)d_ws;
  float* user_x  = w; w += (size_t)Ncust * 32;
  float* item_x0 = w; w += (size_t)Nitem * 32;
  float* bufC    = w; w += (size_t)Ncust * HC;   // xl1 -> (conv2 xl2 in first 20k rows)
  float* bufD    = w; w += (size_t)Nitem * HC;   // xr1 -> agg1 (k_gat in-place)
  float* bufE    = w; w += (size_t)Ncust * HC;   // xr2 -> agg2 (k_gat in-place)
  int* hist1   = (int*)w; w += Nitem;
  int* starts1 = (int*)w; w += Nitem;
  int* cursor1 = (int*)w; w += Nitem;
  int* hist2   = (int*)w; w += Ncust;
  int* starts2 = (int*)w; w += Ncust;
  int* cursor2 = (int*)w; w += Ncust;
  int* partials = (int*)w; w += 512;
  int2* ebuf1 = (int2*)w; w += (size_t)E * 2;
  int2* ebuf2 = (int2*)w; w += (size_t)E * 2;
  if ((size_t)((char*)w - (char*)d_ws) > ws_size) return;

  float* out_scores = (float*)d_out;
  float* out_z      = out_scores + Ncust;

  const int egrid = (E + 255) / 256;
  const int nb1 = (Nitem + SCAN_BLK - 1) / SCAN_BLK;
  const int nb2 = (Ncust + SCAN_BLK - 1) / SCAN_BLK;
  const int nt1 = (Ncust + 127) / 128;
  const int nt2 = (Nitem + 127) / 128;

  // -------- CSR build --------
  hipMemsetAsync(hist1, 0, (size_t)Nitem * 4, stream);
  hipMemsetAsync(hist2, 0, (size_t)Ncust * 4, stream);
  k_hist<<<egrid, 256, 0, stream>>>(edge_dst, hist1, E);
  k_hist<<<egrid, 256, 0, stream>>>(edge_src, hist2, E);
  k_scan_local<<<nb1, SCAN_T, 0, stream>>>(hist1, starts1, partials, Nitem);
  k_scan_partials<<<1, SCAN_T, 0, stream>>>(partials, nb1);
  k_scan_add<<<(Nitem + 255) / 256, 256, 0, stream>>>(starts1, partials, cursor1, Nitem);
  k_scatter<<<egrid, 256, 0, stream>>>(edge_dst, edge_src, cursor1, ebuf1, E);
  k_scan_local<<<nb2, SCAN_T, 0, stream>>>(hist2, starts2, partials, Ncust);
  k_scan_partials<<<1, SCAN_T, 0, stream>>>(partials, nb2);
  k_scan_add<<<(Ncust + 255) / 256, 256, 0, stream>>>(starts2, partials, cursor2, Ncust);
  k_scatter<<<egrid, 256, 0, stream>>>(edge_src, edge_dst, cursor2, ebuf2, E);

  // -------- node projections --------
  k_proj101<<<(Ncust + 63) / 64, 256, 0, stream>>>(customer_x, user_W, user_b, user_x, Ncust);
  k_item_proj<<<(Nitem * 32 + 255) / 256, 256, 0, stream>>>(fund_x, item_W, item_b, item_x0, Nitem);

  // -------- conv linear parts from user_x (xl1 + xr2 in one pass) --------
  k_dual32<<<nt1, 256, 0, stream>>>(user_x, c1_Wl, c1_bl, c2_Wr, c2_br, bufC, bufE, Ncust);
  k_tile<32, 0, 0><<<nt2, 256, 0, stream>>>(item_x0, nullptr, c1_Wr, c1_br, bufD, Nitem);

  // -------- conv1 edge phase (customer -> fund), agg1 in-place into bufD --------
  k_gat<1><<<(Nitem + 3) / 4, 256, 0, stream>>>(bufC, bufD, ebuf1, starts1, hist1,
                                                c1_att, edge_attr, c1_We, bufD, Nitem);

  // -------- conv2: xl2 = relu(agg1+c1_bias)@c2_Wl+c2_bl into bufC; edge phase in-place bufE --------
  k_tile<128, 1, 0><<<nt2, 256, 0, stream>>>(bufD, c1_bias, c2_Wl, c2_bl, bufC, Nitem);
  k_gat<0><<<(Ncust + 3) / 4, 256, 0, stream>>>(bufC, bufE, ebuf2, starts2, hist2,
                                                c2_att, nullptr, nullptr, bufE, Ncust);

  // -------- fused head: proj1 + cls + proj2 --------
  k_head_fused<<<nt1, 256, 0, stream>>>(bufE, c2_bias, proj_W1, proj_b1, proj_W2, proj_b2,
                                        cls_W1, cls_b1, cls_W2, cls_b2,
                                        out_z, out_scores, Ncust);
}